// Round 5
// baseline (1314.614 us; speedup 1.0000x reference)
//
#include <hip/hip_runtime.h>

#define EPSV 1e-5f
#define BCAP 1280   // bucket capacity: Binomial(1.6M, 64/100K) mean 1024, sd 32 -> +8 sd

static __device__ __forceinline__ ushort f2bf(float f) {
    unsigned u = __float_as_uint(f);
    unsigned r = (u + 0x7FFF + ((u >> 16) & 1)) >> 16;   // RTNE
    return (ushort)r;
}
static __device__ __forceinline__ float bf2f(ushort b) {
    return __uint_as_float(((unsigned)b) << 16);
}

// ---------------- CSR build: bucketed counting sort ----------------
// Bucket = 64 consecutive dst ids (~1024 edges). Pass 1 scatters packed edges
// into per-bucket windows (sequential-within-5KB -> no write amplification).
// Pass 2: one block per bucket builds the padded CSR contiguously.

__global__ void bucket_scatter(const int* __restrict__ src, const int* __restrict__ dst,
                               int* __restrict__ bcnt, int* __restrict__ bbuf, int E) {
    int i = blockIdx.x * blockDim.x + threadIdx.x;
    if (i < E) {
        int d = dst[i];
        int b = d >> 6;
        int p = atomicAdd(&bcnt[b], 1);
        if (p < BCAP) bbuf[(size_t)b * BCAP + p] = ((d & 63) << 17) | src[i];
    }
}

__global__ __launch_bounds__(256) void bucket_build(
    const int* __restrict__ bcnt, const int* __restrict__ bbuf, int* __restrict__ cursor,
    int2* __restrict__ seg, int* __restrict__ col, int n)
{
    __shared__ int lcnt[64], loff[64], lcur[64];
    __shared__ int sbase;
    int b = blockIdx.x;
    int node0 = b << 6;
    int t = threadIdx.x;
    if (t < 64) lcnt[t] = 0;
    __syncthreads();

    int cnt = min(bcnt[b], BCAP);
    const int* __restrict__ eb = bbuf + (size_t)b * BCAP;
    for (int i = t; i < cnt; i += 256) atomicAdd(&lcnt[eb[i] >> 17], 1);
    __syncthreads();

    if (t < 64) {                       // wave 0: scan of padded counts
        int pc = (lcnt[t] + 7) & ~7;
        int pre = pc;
        for (int d = 1; d < 64; d <<= 1) {
            int tm = __shfl_up(pre, d);
            if (t >= d) pre += tm;
        }
        loff[t] = pre - pc;
        if (t == 63) sbase = atomicAdd(cursor, pre);
    }
    __syncthreads();
    int base = sbase;
    if (t < 64) {
        lcur[t] = base + loff[t];
        if (node0 + t < n) seg[node0 + t] = make_int2(base + loff[t], lcnt[t]);
    }
    __syncthreads();

    for (int i = t; i < cnt; i += 256) {
        int e = eb[i];
        int p = atomicAdd(&lcur[e >> 17], 1);
        col[p] = e & 0x1FFFF;
    }
    __syncthreads();
    if (t < 64) {                       // pads -> zero row n
        int pend = base + loff[t] + ((lcnt[t] + 7) & ~7);
        for (int p = base + loff[t] + lcnt[t]; p < pend; ++p) col[p] = n;
    }
}

// ---------------- transform, DIN=7: yl = x@Wl (bf16) ; h = x@Wr + bl ----------------

__global__ __launch_bounds__(512) void transform7(
    const float* __restrict__ x,
    const float* __restrict__ Wl, const float* __restrict__ bl, const float* __restrict__ Wr,
    ushort* __restrict__ yl, float* __restrict__ h, int n)
{
    __shared__ float swl[7 * 64], swr[7 * 64], sbl[64];
    for (int i = threadIdx.x; i < 7 * 64; i += 512) { swl[i] = Wl[i]; swr[i] = Wr[i]; }
    if (threadIdx.x < 64) sbl[threadIdx.x] = bl[threadIdx.x];
    __syncthreads();

    if (blockIdx.x == 0 && threadIdx.x < 64) yl[(size_t)n * 64 + threadIdx.x] = 0;  // pad row

    int lane = threadIdx.x & 63;
    int node = blockIdx.x * 8 + (threadIdx.x >> 6);
    if (node >= n) return;

    float xv = (lane < 7) ? x[(size_t)node * 7 + lane] : 0.f;
    float hl = 0.f, hr = sbl[lane];
#pragma unroll
    for (int k = 0; k < 7; ++k) {
        float xk = __shfl(xv, k);
        hl += xk * swl[k * 64 + lane];
        hr += xk * swr[k * 64 + lane];
    }
    yl[(size_t)node * 64 + lane] = f2bf(hl);
    h[(size_t)node * 64 + lane] = hr;
}

// ---------------- transform, DIN=64: z = relu(BN(zin)); yl = z@Wl (bf16); h = z@Wr + bl ----

__global__ __launch_bounds__(256) void transform64(
    const float* __restrict__ zin, const float* __restrict__ scale, const float* __restrict__ shift,
    const float* __restrict__ Wl, const float* __restrict__ Wr, const float* __restrict__ bl,
    ushort* __restrict__ yl, float* __restrict__ h, int n)
{
    __shared__ float zt[64][68];
    __shared__ float swl[64 * 64];
    __shared__ float swr[64 * 64];
    __shared__ float ssc[64], ssh[64], sbl[64];

    int t = threadIdx.x;
    if (t < 64) { ssc[t] = scale[t]; ssh[t] = shift[t]; sbl[t] = bl[t]; }
    for (int i = t; i < 4096; i += 256) { swl[i] = Wl[i]; swr[i] = Wr[i]; }
    __syncthreads();

    int node0 = blockIdx.x * 64;
    {
        int m = t >> 2, c4 = (t & 3) * 16;
        int gm = node0 + m;
        if (gm < n) {
            const float4* zp = reinterpret_cast<const float4*>(zin + (size_t)gm * 64 + c4);
#pragma unroll
            for (int j = 0; j < 4; ++j) {
                float4 v = zp[j];
                int c = c4 + j * 4;
                v.x = fmaxf(v.x * ssc[c + 0] + ssh[c + 0], 0.f);
                v.y = fmaxf(v.y * ssc[c + 1] + ssh[c + 1], 0.f);
                v.z = fmaxf(v.z * ssc[c + 2] + ssh[c + 2], 0.f);
                v.w = fmaxf(v.w * ssc[c + 3] + ssh[c + 3], 0.f);
                zt[m][c + 0] = v.x; zt[m][c + 1] = v.y; zt[m][c + 2] = v.z; zt[m][c + 3] = v.w;
            }
        } else {
#pragma unroll
            for (int j = 0; j < 16; ++j) zt[m][c4 + j] = 0.f;
        }
    }
    __syncthreads();

    int ng = t >> 4;            // nodes ng*4..+3
    int cg = t & 15;            // cg<8 -> Wl (yl out), cg>=8 -> Wr (h out)
    int mb = ng * 4;
    const float* sw = (cg < 8) ? swl : swr;
    int c0 = (cg & 7) * 8;

    float acc[4][8];
#pragma unroll
    for (int i = 0; i < 4; ++i)
#pragma unroll
        for (int j = 0; j < 8; ++j) acc[i][j] = 0.f;

#pragma unroll 4
    for (int k = 0; k < 64; ++k) {
        float z0 = zt[mb + 0][k];
        float z1 = zt[mb + 1][k];
        float z2 = zt[mb + 2][k];
        float z3 = zt[mb + 3][k];
        float4 wa = *reinterpret_cast<const float4*>(sw + k * 64 + c0);
        float4 wb = *reinterpret_cast<const float4*>(sw + k * 64 + c0 + 4);
        float w[8] = {wa.x, wa.y, wa.z, wa.w, wb.x, wb.y, wb.z, wb.w};
#pragma unroll
        for (int j = 0; j < 8; ++j) {
            acc[0][j] += z0 * w[j];
            acc[1][j] += z1 * w[j];
            acc[2][j] += z2 * w[j];
            acc[3][j] += z3 * w[j];
        }
    }

#pragma unroll
    for (int i = 0; i < 4; ++i) {
        int gm = node0 + mb + i;
        if (gm >= n) continue;
        if (cg < 8) {
            uint4 pk;
            pk.x = (unsigned)f2bf(acc[i][0]) | ((unsigned)f2bf(acc[i][1]) << 16);
            pk.y = (unsigned)f2bf(acc[i][2]) | ((unsigned)f2bf(acc[i][3]) << 16);
            pk.z = (unsigned)f2bf(acc[i][4]) | ((unsigned)f2bf(acc[i][5]) << 16);
            pk.w = (unsigned)f2bf(acc[i][6]) | ((unsigned)f2bf(acc[i][7]) << 16);
            *reinterpret_cast<uint4*>(yl + (size_t)gm * 64 + c0) = pk;
        } else {
            float* dp = h + (size_t)gm * 64 + c0;
            *reinterpret_cast<float4*>(dp) =
                make_float4(acc[i][0] + sbl[c0 + 0], acc[i][1] + sbl[c0 + 1],
                            acc[i][2] + sbl[c0 + 2], acc[i][3] + sbl[c0 + 3]);
            *reinterpret_cast<float4*>(dp + 4) =
                make_float4(acc[i][4] + sbl[c0 + 4], acc[i][5] + sbl[c0 + 5],
                            acc[i][6] + sbl[c0 + 6], acc[i][7] + sbl[c0 + 7]);
        }
    }
}

// ---------------- gather + fused BN stats: h[i] += mean_j yl[col_j] ----------------

__global__ __launch_bounds__(512) void gather_kernel(
    const ushort* __restrict__ yl, float* __restrict__ h,
    const int* __restrict__ col, const int2* __restrict__ seg,
    float* __restrict__ sums, int n)
{
    __shared__ float ls[128];
    int lane = threadIdx.x & 63;
    int node = blockIdx.x * 8 + (threadIdx.x >> 6);
    bool active = node < n;

    float hv = 0.f;
    if (active) {
        int2 sc = seg[node];
        int s0  = __builtin_amdgcn_readfirstlane(sc.x);
        int deg = __builtin_amdgcn_readfirstlane(sc.y);
        int pc  = (deg + 7) & ~7;
        const int* __restrict__ cp = col + s0;

        float a0 = 0.f, a1 = 0.f, a2 = 0.f, a3 = 0.f;
        float a4 = 0.f, a5 = 0.f, a6 = 0.f, a7 = 0.f;
        for (int j0 = 0; j0 < pc; j0 += 8) {
            int4 ia = *reinterpret_cast<const int4*>(cp + j0);
            int4 ib = *reinterpret_cast<const int4*>(cp + j0 + 4);
            int i0 = __builtin_amdgcn_readfirstlane(ia.x);
            int i1 = __builtin_amdgcn_readfirstlane(ia.y);
            int i2 = __builtin_amdgcn_readfirstlane(ia.z);
            int i3 = __builtin_amdgcn_readfirstlane(ia.w);
            int i4 = __builtin_amdgcn_readfirstlane(ib.x);
            int i5 = __builtin_amdgcn_readfirstlane(ib.y);
            int i6 = __builtin_amdgcn_readfirstlane(ib.z);
            int i7 = __builtin_amdgcn_readfirstlane(ib.w);
            a0 += bf2f(yl[(size_t)i0 * 64 + lane]);
            a1 += bf2f(yl[(size_t)i1 * 64 + lane]);
            a2 += bf2f(yl[(size_t)i2 * 64 + lane]);
            a3 += bf2f(yl[(size_t)i3 * 64 + lane]);
            a4 += bf2f(yl[(size_t)i4 * 64 + lane]);
            a5 += bf2f(yl[(size_t)i5 * 64 + lane]);
            a6 += bf2f(yl[(size_t)i6 * 64 + lane]);
            a7 += bf2f(yl[(size_t)i7 * 64 + lane]);
        }
        float agg = (((a0 + a1) + (a2 + a3)) + ((a4 + a5) + (a6 + a7))) * (1.f / (float)max(deg, 1));
        size_t idx = (size_t)node * 64 + lane;
        hv = h[idx] + agg;
        h[idx] = hv;
    }
    if (threadIdx.x < 128) ls[threadIdx.x] = 0.f;
    __syncthreads();
    if (active) {
        atomicAdd(&ls[lane], hv);
        atomicAdd(&ls[64 + lane], hv * hv);
    }
    __syncthreads();
    if (threadIdx.x < 128) atomicAdd(&sums[threadIdx.x], ls[threadIdx.x]);
}

__global__ void bn_finalize(const float* __restrict__ sums, const float* __restrict__ g,
                            const float* __restrict__ be, float* __restrict__ scale,
                            float* __restrict__ shift, int n) {
    int c = threadIdx.x;
    if (c < 64) {
        float inv_n = 1.f / (float)n;
        float mu = sums[c] * inv_n;
        float var = sums[64 + c] * inv_n - mu * mu;
        float sc = g[c] * rsqrtf(var + EPSV);
        scale[c] = sc;
        shift[c] = be[c] - mu * sc;
    }
}

// ---------------- output head: relu(BN(h)) @ Wo + bo ----------------

__global__ __launch_bounds__(256) void out_kernel(const float* __restrict__ h,
                                                  const float* __restrict__ scale,
                                                  const float* __restrict__ shift,
                                                  const float* __restrict__ Wo,
                                                  const float* __restrict__ bo,
                                                  float* __restrict__ out, int n) {
    int lane = threadIdx.x & 63;
    int wave = threadIdx.x >> 6;
    int node = blockIdx.x * 4 + wave;
    if (node >= n) return;
    float v = h[(size_t)node * 64 + lane];
    v = fmaxf(v * scale[lane] + shift[lane], 0.f);
    float p = v * Wo[lane];
    for (int d = 32; d > 0; d >>= 1) p += __shfl_xor(p, d);
    if (lane == 0) out[node] = p + bo[0];
}

// ---------------- launch ----------------

extern "C" void kernel_launch(void* const* d_in, const int* in_sizes, int n_in,
                              void* d_out, int out_size, void* d_ws, size_t ws_size,
                              hipStream_t stream) {
    const float* x   = (const float*)d_in[0];
    const int*   ei  = (const int*)d_in[1];
    const float* Wl0 = (const float*)d_in[2];
    const float* bl0 = (const float*)d_in[3];
    const float* Wr0 = (const float*)d_in[4];
    const float* g0  = (const float*)d_in[5];
    const float* be0 = (const float*)d_in[6];
    const float* Wl1 = (const float*)d_in[7];
    const float* bl1 = (const float*)d_in[8];
    const float* Wr1 = (const float*)d_in[9];
    const float* g1  = (const float*)d_in[10];
    const float* be1 = (const float*)d_in[11];
    const float* Wl2 = (const float*)d_in[12];
    const float* bl2 = (const float*)d_in[13];
    const float* Wr2 = (const float*)d_in[14];
    const float* g2  = (const float*)d_in[15];
    const float* be2 = (const float*)d_in[16];
    const float* Wo  = (const float*)d_in[17];
    const float* bo  = (const float*)d_in[18];

    const int N = in_sizes[0] / 7;
    const int E = in_sizes[1] / 2;
    const int NB = (N + 63) / 64;
    const int* srcp = ei;
    const int* dstp = ei + E;

    char* ws = (char*)d_ws;
    size_t off = 0;
    auto walloc = [&](size_t bytes) -> void* {
        void* p = ws + off;
        off = (off + bytes + 255) & ~(size_t)255;
        return p;
    };
    int*    bcnt   = (int*)walloc((size_t)(NB + 1) * sizeof(int));   // cursor at bcnt[NB]
    int*    cursor = bcnt + NB;
    int*    bbuf   = (int*)walloc((size_t)NB * BCAP * sizeof(int));
    int2*   seg    = (int2*)walloc((size_t)N * sizeof(int2));
    int*    col    = (int*)walloc(((size_t)E + 7 * (size_t)N + 64) * sizeof(int));
    float*  sums   = (float*)walloc(3 * 128 * sizeof(float));
    float*  scale  = (float*)walloc(3 * 64 * sizeof(float));
    float*  shift  = (float*)walloc(3 * 64 * sizeof(float));
    ushort* yl     = (ushort*)walloc(((size_t)N + 1) * 64 * sizeof(ushort));  // row N = zeros
    float*  h0     = (float*)walloc((size_t)N * 64 * sizeof(float));
    float*  h1     = (float*)walloc((size_t)N * 64 * sizeof(float));

    hipMemsetAsync(bcnt, 0, (size_t)(NB + 1) * sizeof(int), stream);
    hipMemsetAsync(sums, 0, 3 * 128 * sizeof(float), stream);

    bucket_scatter<<<(E + 255) / 256, 256, 0, stream>>>(srcp, dstp, bcnt, bbuf, E);
    bucket_build<<<NB, 256, 0, stream>>>(bcnt, bbuf, cursor, seg, col, N);

    const int gw = (N + 7) / 8;       // wave-per-node grids (512 threads)
    const int gt = (N + 63) / 64;     // transform64 tiles

    // ---- layer 0 ----
    transform7<<<gw, 512, 0, stream>>>(x, Wl0, bl0, Wr0, yl, h0, N);
    gather_kernel<<<gw, 512, 0, stream>>>(yl, h0, col, seg, sums, N);
    bn_finalize<<<1, 64, 0, stream>>>(sums, g0, be0, scale, shift, N);

    // ---- layer 1 ----
    transform64<<<gt, 256, 0, stream>>>(h0, scale, shift, Wl1, Wr1, bl1, yl, h1, N);
    gather_kernel<<<gw, 512, 0, stream>>>(yl, h1, col, seg, sums + 128, N);
    bn_finalize<<<1, 64, 0, stream>>>(sums + 128, g1, be1, scale + 64, shift + 64, N);

    // ---- layer 2 ----
    transform64<<<gt, 256, 0, stream>>>(h1, scale + 64, shift + 64, Wl2, Wr2, bl2, yl, h0, N);
    gather_kernel<<<gw, 512, 0, stream>>>(yl, h0, col, seg, sums + 256, N);
    bn_finalize<<<1, 64, 0, stream>>>(sums + 256, g2, be2, scale + 128, shift + 128, N);

    out_kernel<<<(N + 3) / 4, 256, 0, stream>>>(h0, scale + 128, shift + 128, Wo, bo, (float*)d_out, N);
}

// Round 6
// 598.420 us; speedup vs baseline: 2.1968x; 2.1968x over previous
//
#include <hip/hip_runtime.h>

#define EPSV 1e-5f
#define BCAP 1280   // bucket capacity: Binomial(1.6M, 64/100K) mean 1024, sd 32 -> +8 sd

static __device__ __forceinline__ ushort f2bf(float f) {
    unsigned u = __float_as_uint(f);
    unsigned r = (u + 0x7FFF + ((u >> 16) & 1)) >> 16;   // RTNE
    return (ushort)r;
}

// ---------------- CSR build: bucketed counting sort ----------------
// Bucket = 64 consecutive dst ids (~1024 edges). Pass 1 scatters packed edges
// into per-bucket windows (sequential-within-5KB -> no write amplification).
// Pass 2: one block per bucket builds the padded CSR contiguously.
// Segments padded to multiple of 16 with index n (zero row).

__global__ void bucket_scatter(const int* __restrict__ src, const int* __restrict__ dst,
                               int* __restrict__ bcnt, int* __restrict__ bbuf, int E) {
    int i = blockIdx.x * blockDim.x + threadIdx.x;
    if (i < E) {
        int d = dst[i];
        int b = d >> 6;
        int p = atomicAdd(&bcnt[b], 1);
        if (p < BCAP) bbuf[(size_t)b * BCAP + p] = ((d & 63) << 17) | src[i];
    }
}

__global__ __launch_bounds__(256) void bucket_build(
    const int* __restrict__ bcnt, const int* __restrict__ bbuf, int* __restrict__ cursor,
    int2* __restrict__ seg, int* __restrict__ col, int n)
{
    __shared__ int lcnt[64], loff[64], lcur[64];
    __shared__ int sbase;
    int b = blockIdx.x;
    int node0 = b << 6;
    int t = threadIdx.x;
    if (t < 64) lcnt[t] = 0;
    __syncthreads();

    int cnt = min(bcnt[b], BCAP);
    const int* __restrict__ eb = bbuf + (size_t)b * BCAP;
    for (int i = t; i < cnt; i += 256) atomicAdd(&lcnt[eb[i] >> 17], 1);
    __syncthreads();

    if (t < 64) {                       // wave 0: scan of padded counts
        int pc = (lcnt[t] + 15) & ~15;
        int pre = pc;
        for (int d = 1; d < 64; d <<= 1) {
            int tm = __shfl_up(pre, d);
            if (t >= d) pre += tm;
        }
        loff[t] = pre - pc;
        if (t == 63) sbase = atomicAdd(cursor, pre);
    }
    __syncthreads();
    int base = sbase;
    if (t < 64) {
        lcur[t] = base + loff[t];
        if (node0 + t < n) seg[node0 + t] = make_int2(base + loff[t], lcnt[t]);
    }
    __syncthreads();

    for (int i = t; i < cnt; i += 256) {
        int e = eb[i];
        int p = atomicAdd(&lcur[e >> 17], 1);
        col[p] = e & 0x1FFFF;
    }
    __syncthreads();
    if (t < 64) {                       // pads -> zero row n
        int pend = base + loff[t] + ((lcnt[t] + 15) & ~15);
        for (int p = base + loff[t] + lcnt[t]; p < pend; ++p) col[p] = n;
    }
}

// ---------------- transform, DIN=7: yl = x@Wl (bf16) ; h = x@Wr + bl ----------------

__global__ __launch_bounds__(512) void transform7(
    const float* __restrict__ x,
    const float* __restrict__ Wl, const float* __restrict__ bl, const float* __restrict__ Wr,
    ushort* __restrict__ yl, float* __restrict__ h, int n)
{
    __shared__ float swl[7 * 64], swr[7 * 64], sbl[64];
    for (int i = threadIdx.x; i < 7 * 64; i += 512) { swl[i] = Wl[i]; swr[i] = Wr[i]; }
    if (threadIdx.x < 64) sbl[threadIdx.x] = bl[threadIdx.x];
    __syncthreads();

    if (blockIdx.x == 0 && threadIdx.x < 64) yl[(size_t)n * 64 + threadIdx.x] = 0;  // pad row

    int lane = threadIdx.x & 63;
    int node = blockIdx.x * 8 + (threadIdx.x >> 6);
    if (node >= n) return;

    float xv = (lane < 7) ? x[(size_t)node * 7 + lane] : 0.f;
    float hl = 0.f, hr = sbl[lane];
#pragma unroll
    for (int k = 0; k < 7; ++k) {
        float xk = __shfl(xv, k);
        hl += xk * swl[k * 64 + lane];
        hr += xk * swr[k * 64 + lane];
    }
    yl[(size_t)node * 64 + lane] = f2bf(hl);
    h[(size_t)node * 64 + lane] = hr;
}

// ---------------- transform, DIN=64: z = relu(BN(zin)); yl = z@Wl (bf16); h = z@Wr + bl ----

__global__ __launch_bounds__(256) void transform64(
    const float* __restrict__ zin, const float* __restrict__ scale, const float* __restrict__ shift,
    const float* __restrict__ Wl, const float* __restrict__ Wr, const float* __restrict__ bl,
    ushort* __restrict__ yl, float* __restrict__ h, int n)
{
    __shared__ float zt[64][68];
    __shared__ float swl[64 * 64];
    __shared__ float swr[64 * 64];
    __shared__ float ssc[64], ssh[64], sbl[64];

    int t = threadIdx.x;
    if (t < 64) { ssc[t] = scale[t]; ssh[t] = shift[t]; sbl[t] = bl[t]; }
    for (int i = t; i < 4096; i += 256) { swl[i] = Wl[i]; swr[i] = Wr[i]; }
    __syncthreads();

    int node0 = blockIdx.x * 64;
    {
        int m = t >> 2, c4 = (t & 3) * 16;
        int gm = node0 + m;
        if (gm < n) {
            const float4* zp = reinterpret_cast<const float4*>(zin + (size_t)gm * 64 + c4);
#pragma unroll
            for (int j = 0; j < 4; ++j) {
                float4 v = zp[j];
                int c = c4 + j * 4;
                v.x = fmaxf(v.x * ssc[c + 0] + ssh[c + 0], 0.f);
                v.y = fmaxf(v.y * ssc[c + 1] + ssh[c + 1], 0.f);
                v.z = fmaxf(v.z * ssc[c + 2] + ssh[c + 2], 0.f);
                v.w = fmaxf(v.w * ssc[c + 3] + ssh[c + 3], 0.f);
                zt[m][c + 0] = v.x; zt[m][c + 1] = v.y; zt[m][c + 2] = v.z; zt[m][c + 3] = v.w;
            }
        } else {
#pragma unroll
            for (int j = 0; j < 16; ++j) zt[m][c4 + j] = 0.f;
        }
    }
    __syncthreads();

    int ng = t >> 4;            // nodes ng*4..+3
    int cg = t & 15;            // cg<8 -> Wl (yl out), cg>=8 -> Wr (h out)
    int mb = ng * 4;
    const float* sw = (cg < 8) ? swl : swr;
    int c0 = (cg & 7) * 8;

    float acc[4][8];
#pragma unroll
    for (int i = 0; i < 4; ++i)
#pragma unroll
        for (int j = 0; j < 8; ++j) acc[i][j] = 0.f;

#pragma unroll 4
    for (int k = 0; k < 64; ++k) {
        float z0 = zt[mb + 0][k];
        float z1 = zt[mb + 1][k];
        float z2 = zt[mb + 2][k];
        float z3 = zt[mb + 3][k];
        float4 wa = *reinterpret_cast<const float4*>(sw + k * 64 + c0);
        float4 wb = *reinterpret_cast<const float4*>(sw + k * 64 + c0 + 4);
        float w[8] = {wa.x, wa.y, wa.z, wa.w, wb.x, wb.y, wb.z, wb.w};
#pragma unroll
        for (int j = 0; j < 8; ++j) {
            acc[0][j] += z0 * w[j];
            acc[1][j] += z1 * w[j];
            acc[2][j] += z2 * w[j];
            acc[3][j] += z3 * w[j];
        }
    }

#pragma unroll
    for (int i = 0; i < 4; ++i) {
        int gm = node0 + mb + i;
        if (gm >= n) continue;
        if (cg < 8) {
            uint4 pk;
            pk.x = (unsigned)f2bf(acc[i][0]) | ((unsigned)f2bf(acc[i][1]) << 16);
            pk.y = (unsigned)f2bf(acc[i][2]) | ((unsigned)f2bf(acc[i][3]) << 16);
            pk.z = (unsigned)f2bf(acc[i][4]) | ((unsigned)f2bf(acc[i][5]) << 16);
            pk.w = (unsigned)f2bf(acc[i][6]) | ((unsigned)f2bf(acc[i][7]) << 16);
            *reinterpret_cast<uint4*>(yl + (size_t)gm * 64 + c0) = pk;
        } else {
            float* dp = h + (size_t)gm * 64 + c0;
            *reinterpret_cast<float4*>(dp) =
                make_float4(acc[i][0] + sbl[c0 + 0], acc[i][1] + sbl[c0 + 1],
                            acc[i][2] + sbl[c0 + 2], acc[i][3] + sbl[c0 + 3]);
            *reinterpret_cast<float4*>(dp + 4) =
                make_float4(acc[i][4] + sbl[c0 + 4], acc[i][5] + sbl[c0 + 5],
                            acc[i][6] + sbl[c0 + 6], acc[i][7] + sbl[c0 + 7]);
        }
    }
}

// ---------------- gather: h[i] += mean_j yl[col_j] ----------------
// Wave per node. Lane owns column pair (2c,2c+1) as one dword of 2 bf16.
// Lane halves 0-31 / 32-63 take even/odd neighbors: 8 dword loads = 16 neighbors.

__global__ __launch_bounds__(512) void gather_kernel(
    const ushort* __restrict__ yl, float* __restrict__ h,
    const int* __restrict__ col, const int2* __restrict__ seg, int n)
{
    int lane = threadIdx.x & 63;
    int node = blockIdx.x * 8 + (threadIdx.x >> 6);
    if (node >= n) return;

    int2 sc = seg[node];
    int s0  = __builtin_amdgcn_readfirstlane(sc.x);
    int deg = __builtin_amdgcn_readfirstlane(sc.y);
    int pc  = (deg + 15) & ~15;
    const int* __restrict__ cp = col + s0;

    bool hi = lane >= 32;
    unsigned cl = (unsigned)(lane & 31);          // columns 2cl, 2cl+1
    const unsigned* __restrict__ ylu = reinterpret_cast<const unsigned*>(yl);  // row stride 32

    float alo = 0.f, ahi = 0.f;
    for (int j0 = 0; j0 < pc; j0 += 16) {
        int4 ia = *reinterpret_cast<const int4*>(cp + j0);
        int4 ib = *reinterpret_cast<const int4*>(cp + j0 + 4);
        int4 ic = *reinterpret_cast<const int4*>(cp + j0 + 8);
        int4 id = *reinterpret_cast<const int4*>(cp + j0 + 12);
        unsigned p0 = (unsigned)(hi ? ia.y : ia.x);
        unsigned p1 = (unsigned)(hi ? ia.w : ia.z);
        unsigned p2 = (unsigned)(hi ? ib.y : ib.x);
        unsigned p3 = (unsigned)(hi ? ib.w : ib.z);
        unsigned p4 = (unsigned)(hi ? ic.y : ic.x);
        unsigned p5 = (unsigned)(hi ? ic.w : ic.z);
        unsigned p6 = (unsigned)(hi ? id.y : id.x);
        unsigned p7 = (unsigned)(hi ? id.w : id.z);
        unsigned u0 = ylu[(p0 << 5) + cl];
        unsigned u1 = ylu[(p1 << 5) + cl];
        unsigned u2 = ylu[(p2 << 5) + cl];
        unsigned u3 = ylu[(p3 << 5) + cl];
        unsigned u4 = ylu[(p4 << 5) + cl];
        unsigned u5 = ylu[(p5 << 5) + cl];
        unsigned u6 = ylu[(p6 << 5) + cl];
        unsigned u7 = ylu[(p7 << 5) + cl];
        alo += __uint_as_float(u0 << 16);           ahi += __uint_as_float(u0 & 0xFFFF0000u);
        alo += __uint_as_float(u1 << 16);           ahi += __uint_as_float(u1 & 0xFFFF0000u);
        alo += __uint_as_float(u2 << 16);           ahi += __uint_as_float(u2 & 0xFFFF0000u);
        alo += __uint_as_float(u3 << 16);           ahi += __uint_as_float(u3 & 0xFFFF0000u);
        alo += __uint_as_float(u4 << 16);           ahi += __uint_as_float(u4 & 0xFFFF0000u);
        alo += __uint_as_float(u5 << 16);           ahi += __uint_as_float(u5 & 0xFFFF0000u);
        alo += __uint_as_float(u6 << 16);           ahi += __uint_as_float(u6 & 0xFFFF0000u);
        alo += __uint_as_float(u7 << 16);           ahi += __uint_as_float(u7 & 0xFFFF0000u);
    }
    alo += __shfl_xor(alo, 32);
    ahi += __shfl_xor(ahi, 32);
    if (!hi) {
        float inv = 1.f / (float)max(deg, 1);
        float2* hp = reinterpret_cast<float2*>(h + (size_t)node * 64 + 2 * cl);
        float2 hv = *hp;
        hv.x += alo * inv;
        hv.y += ahi * inv;
        *hp = hv;
    }
}

// ---------------- BN statistics ----------------

__global__ __launch_bounds__(256) void bn_stats(const float* __restrict__ h,
                                                float* __restrict__ sums, int n) {
    __shared__ float ls[128];
    if (threadIdx.x < 128) ls[threadIdx.x] = 0.f;
    __syncthreads();
    size_t total = (size_t)n * 64;
    size_t stride = (size_t)gridDim.x * 1024;
    float s0 = 0.f, s1 = 0.f, s2 = 0.f, s3 = 0.f;
    float q0 = 0.f, q1 = 0.f, q2 = 0.f, q3 = 0.f;
    for (size_t i = (size_t)blockIdx.x * 1024 + (size_t)threadIdx.x * 4; i < total; i += stride) {
        float4 v = *reinterpret_cast<const float4*>(h + i);
        s0 += v.x; q0 += v.x * v.x;
        s1 += v.y; q1 += v.y * v.y;
        s2 += v.z; q2 += v.z * v.z;
        s3 += v.w; q3 += v.w * v.w;
    }
    int c = (threadIdx.x * 4) & 63;
    atomicAdd(&ls[c + 0], s0); atomicAdd(&ls[c + 1], s1);
    atomicAdd(&ls[c + 2], s2); atomicAdd(&ls[c + 3], s3);
    atomicAdd(&ls[64 + c + 0], q0); atomicAdd(&ls[64 + c + 1], q1);
    atomicAdd(&ls[64 + c + 2], q2); atomicAdd(&ls[64 + c + 3], q3);
    __syncthreads();
    if (threadIdx.x < 128) atomicAdd(&sums[threadIdx.x], ls[threadIdx.x]);
}

__global__ void bn_finalize(const float* __restrict__ sums, const float* __restrict__ g,
                            const float* __restrict__ be, float* __restrict__ scale,
                            float* __restrict__ shift, int n) {
    int c = threadIdx.x;
    if (c < 64) {
        float inv_n = 1.f / (float)n;
        float mu = sums[c] * inv_n;
        float var = sums[64 + c] * inv_n - mu * mu;
        float sc = g[c] * rsqrtf(var + EPSV);
        scale[c] = sc;
        shift[c] = be[c] - mu * sc;
    }
}

// ---------------- output head: relu(BN(h)) @ Wo + bo ----------------

__global__ __launch_bounds__(256) void out_kernel(const float* __restrict__ h,
                                                  const float* __restrict__ scale,
                                                  const float* __restrict__ shift,
                                                  const float* __restrict__ Wo,
                                                  const float* __restrict__ bo,
                                                  float* __restrict__ out, int n) {
    int lane = threadIdx.x & 63;
    int wave = threadIdx.x >> 6;
    int node = blockIdx.x * 4 + wave;
    if (node >= n) return;
    float v = h[(size_t)node * 64 + lane];
    v = fmaxf(v * scale[lane] + shift[lane], 0.f);
    float p = v * Wo[lane];
    for (int d = 32; d > 0; d >>= 1) p += __shfl_xor(p, d);
    if (lane == 0) out[node] = p + bo[0];
}

// ---------------- launch ----------------

extern "C" void kernel_launch(void* const* d_in, const int* in_sizes, int n_in,
                              void* d_out, int out_size, void* d_ws, size_t ws_size,
                              hipStream_t stream) {
    const float* x   = (const float*)d_in[0];
    const int*   ei  = (const int*)d_in[1];
    const float* Wl0 = (const float*)d_in[2];
    const float* bl0 = (const float*)d_in[3];
    const float* Wr0 = (const float*)d_in[4];
    const float* g0  = (const float*)d_in[5];
    const float* be0 = (const float*)d_in[6];
    const float* Wl1 = (const float*)d_in[7];
    const float* bl1 = (const float*)d_in[8];
    const float* Wr1 = (const float*)d_in[9];
    const float* g1  = (const float*)d_in[10];
    const float* be1 = (const float*)d_in[11];
    const float* Wl2 = (const float*)d_in[12];
    const float* bl2 = (const float*)d_in[13];
    const float* Wr2 = (const float*)d_in[14];
    const float* g2  = (const float*)d_in[15];
    const float* be2 = (const float*)d_in[16];
    const float* Wo  = (const float*)d_in[17];
    const float* bo  = (const float*)d_in[18];

    const int N = in_sizes[0] / 7;
    const int E = in_sizes[1] / 2;
    const int NB = (N + 63) / 64;
    const int* srcp = ei;
    const int* dstp = ei + E;

    char* ws = (char*)d_ws;
    size_t off = 0;
    auto walloc = [&](size_t bytes) -> void* {
        void* p = ws + off;
        off = (off + bytes + 255) & ~(size_t)255;
        return p;
    };
    int*    bcnt   = (int*)walloc((size_t)(NB + 1) * sizeof(int));   // cursor at bcnt[NB]
    int*    cursor = bcnt + NB;
    int*    bbuf   = (int*)walloc((size_t)NB * BCAP * sizeof(int));
    int2*   seg    = (int2*)walloc((size_t)N * sizeof(int2));
    int*    col    = (int*)walloc(((size_t)E + 15 * (size_t)N + 64) * sizeof(int));
    float*  sums   = (float*)walloc(3 * 128 * sizeof(float));
    float*  scale  = (float*)walloc(3 * 64 * sizeof(float));
    float*  shift  = (float*)walloc(3 * 64 * sizeof(float));
    ushort* yl     = (ushort*)walloc(((size_t)N + 1) * 64 * sizeof(ushort));  // row N = zeros
    float*  h0     = (float*)walloc((size_t)N * 64 * sizeof(float));
    float*  h1     = (float*)walloc((size_t)N * 64 * sizeof(float));

    hipMemsetAsync(bcnt, 0, (size_t)(NB + 1) * sizeof(int), stream);
    hipMemsetAsync(sums, 0, 3 * 128 * sizeof(float), stream);

    bucket_scatter<<<(E + 255) / 256, 256, 0, stream>>>(srcp, dstp, bcnt, bbuf, E);
    bucket_build<<<NB, 256, 0, stream>>>(bcnt, bbuf, cursor, seg, col, N);

    const int gw = (N + 7) / 8;       // wave-per-node grids (512 threads)
    const int gt = (N + 63) / 64;     // transform64 tiles

    // ---- layer 0 ----
    transform7<<<gw, 512, 0, stream>>>(x, Wl0, bl0, Wr0, yl, h0, N);
    gather_kernel<<<gw, 512, 0, stream>>>(yl, h0, col, seg, N);
    bn_stats<<<1024, 256, 0, stream>>>(h0, sums, N);
    bn_finalize<<<1, 64, 0, stream>>>(sums, g0, be0, scale, shift, N);

    // ---- layer 1 ----
    transform64<<<gt, 256, 0, stream>>>(h0, scale, shift, Wl1, Wr1, bl1, yl, h1, N);
    gather_kernel<<<gw, 512, 0, stream>>>(yl, h1, col, seg, N);
    bn_stats<<<1024, 256, 0, stream>>>(h1, sums + 128, N);
    bn_finalize<<<1, 64, 0, stream>>>(sums + 128, g1, be1, scale + 64, shift + 64, N);

    // ---- layer 2 ----
    transform64<<<gt, 256, 0, stream>>>(h1, scale + 64, shift + 64, Wl2, Wr2, bl2, yl, h0, N);
    gather_kernel<<<gw, 512, 0, stream>>>(yl, h0, col, seg, N);
    bn_stats<<<1024, 256, 0, stream>>>(h0, sums + 256, N);
    bn_finalize<<<1, 64, 0, stream>>>(sums + 256, g2, be2, scale + 128, shift + 128, N);

    out_kernel<<<(N + 3) / 4, 256, 0, stream>>>(h0, scale + 128, shift + 128, Wo, bo, (float*)d_out, N);
}

// Round 7
// 451.222 us; speedup vs baseline: 2.9135x; 1.3262x over previous
//
#include <hip/hip_runtime.h>

#define EPSV 1e-5f
#define BCAP 1280            // bucket capacity: Binomial(1.6M, 64/100K) mean 1024, sd 32 -> +8 sd
#define CWIN (BCAP + 960)    // per-bucket col window: edges + worst-case pad (64 nodes * 15)

static __device__ __forceinline__ ushort f2bf(float f) {
    unsigned u = __float_as_uint(f);
    unsigned r = (u + 0x7FFF + ((u >> 16) & 1)) >> 16;   // RTNE
    return (ushort)r;
}

// ---------------- CSR build: bucketed counting sort ----------------
// Bucket = 64 consecutive dst ids (~1024 edges). Pass 1 scatters packed edges
// into per-bucket windows. Bucket counters are padded to one per 64B cache
// line (bcnt[b*16]) -- same-line L2 atomic serialization was 230us otherwise.
// Pass 2: one block per bucket builds the padded CSR into a STATIC per-bucket
// col window (no global cursor atomics). Segments padded to multiple of 16
// with index n (zero row); inter-segment gaps are never read.

__global__ void bucket_scatter(const int* __restrict__ src, const int* __restrict__ dst,
                               int* __restrict__ bcnt, int* __restrict__ bbuf, int E) {
    int i = blockIdx.x * blockDim.x + threadIdx.x;
    if (i < E) {
        int d = dst[i];
        int b = d >> 6;
        int p = atomicAdd(&bcnt[b * 16], 1);
        if (p < BCAP) bbuf[(size_t)b * BCAP + p] = ((d & 63) << 17) | src[i];
    }
}

__global__ __launch_bounds__(256) void bucket_build(
    const int* __restrict__ bcnt, const int* __restrict__ bbuf,
    int2* __restrict__ seg, int* __restrict__ col, int n)
{
    __shared__ int lcnt[64], loff[64], lcur[64];
    int b = blockIdx.x;
    int node0 = b << 6;
    int t = threadIdx.x;
    if (t < 64) lcnt[t] = 0;
    __syncthreads();

    int cnt = min(bcnt[b * 16], BCAP);
    const int* __restrict__ eb = bbuf + (size_t)b * BCAP;
    for (int i = t; i < cnt; i += 256) atomicAdd(&lcnt[eb[i] >> 17], 1);
    __syncthreads();

    if (t < 64) {                       // wave 0: scan of padded counts
        int pc = (lcnt[t] + 15) & ~15;
        int pre = pc;
        for (int d = 1; d < 64; d <<= 1) {
            int tm = __shfl_up(pre, d);
            if (t >= d) pre += tm;
        }
        loff[t] = pre - pc;
    }
    __syncthreads();
    if (t < 64) {
        int st = b * CWIN + loff[t];
        lcur[t] = st;
        if (node0 + t < n) seg[node0 + t] = make_int2(st, lcnt[t]);
    }
    __syncthreads();

    for (int i = t; i < cnt; i += 256) {
        int e = eb[i];
        int p = atomicAdd(&lcur[e >> 17], 1);
        col[p] = e & 0x1FFFF;
    }
    __syncthreads();
    if (t < 64) {                       // pads -> zero row n
        int st = b * CWIN + loff[t];
        int pend = st + ((lcnt[t] + 15) & ~15);
        for (int p = st + lcnt[t]; p < pend; ++p) col[p] = n;
    }
}

// ---------------- transform, DIN=7: yl = x@Wl (bf16) ; h = x@Wr + bl ----------------

__global__ __launch_bounds__(512) void transform7(
    const float* __restrict__ x,
    const float* __restrict__ Wl, const float* __restrict__ bl, const float* __restrict__ Wr,
    ushort* __restrict__ yl, float* __restrict__ h, int n)
{
    __shared__ float swl[7 * 64], swr[7 * 64], sbl[64];
    for (int i = threadIdx.x; i < 7 * 64; i += 512) { swl[i] = Wl[i]; swr[i] = Wr[i]; }
    if (threadIdx.x < 64) sbl[threadIdx.x] = bl[threadIdx.x];
    __syncthreads();

    if (blockIdx.x == 0 && threadIdx.x < 64) yl[(size_t)n * 64 + threadIdx.x] = 0;  // pad row

    int lane = threadIdx.x & 63;
    int node = blockIdx.x * 8 + (threadIdx.x >> 6);
    if (node >= n) return;

    float xv = (lane < 7) ? x[(size_t)node * 7 + lane] : 0.f;
    float hl = 0.f, hr = sbl[lane];
#pragma unroll
    for (int k = 0; k < 7; ++k) {
        float xk = __shfl(xv, k);
        hl += xk * swl[k * 64 + lane];
        hr += xk * swr[k * 64 + lane];
    }
    yl[(size_t)node * 64 + lane] = f2bf(hl);
    h[(size_t)node * 64 + lane] = hr;
}

// ---------------- transform, DIN=64: z = relu(BN(zin)); yl = z@Wl (bf16); h = z@Wr + bl ----

__global__ __launch_bounds__(256) void transform64(
    const float* __restrict__ zin, const float* __restrict__ scale, const float* __restrict__ shift,
    const float* __restrict__ Wl, const float* __restrict__ Wr, const float* __restrict__ bl,
    ushort* __restrict__ yl, float* __restrict__ h, int n)
{
    __shared__ float zt[64][68];
    __shared__ float swl[64 * 64];
    __shared__ float swr[64 * 64];
    __shared__ float ssc[64], ssh[64], sbl[64];

    int t = threadIdx.x;
    if (t < 64) { ssc[t] = scale[t]; ssh[t] = shift[t]; sbl[t] = bl[t]; }
    for (int i = t; i < 4096; i += 256) { swl[i] = Wl[i]; swr[i] = Wr[i]; }
    __syncthreads();

    int node0 = blockIdx.x * 64;
    {
        int m = t >> 2, c4 = (t & 3) * 16;
        int gm = node0 + m;
        if (gm < n) {
            const float4* zp = reinterpret_cast<const float4*>(zin + (size_t)gm * 64 + c4);
#pragma unroll
            for (int j = 0; j < 4; ++j) {
                float4 v = zp[j];
                int c = c4 + j * 4;
                v.x = fmaxf(v.x * ssc[c + 0] + ssh[c + 0], 0.f);
                v.y = fmaxf(v.y * ssc[c + 1] + ssh[c + 1], 0.f);
                v.z = fmaxf(v.z * ssc[c + 2] + ssh[c + 2], 0.f);
                v.w = fmaxf(v.w * ssc[c + 3] + ssh[c + 3], 0.f);
                zt[m][c + 0] = v.x; zt[m][c + 1] = v.y; zt[m][c + 2] = v.z; zt[m][c + 3] = v.w;
            }
        } else {
#pragma unroll
            for (int j = 0; j < 16; ++j) zt[m][c4 + j] = 0.f;
        }
    }
    __syncthreads();

    int ng = t >> 4;            // nodes ng*4..+3
    int cg = t & 15;            // cg<8 -> Wl (yl out), cg>=8 -> Wr (h out)
    int mb = ng * 4;
    const float* sw = (cg < 8) ? swl : swr;
    int c0 = (cg & 7) * 8;

    float acc[4][8];
#pragma unroll
    for (int i = 0; i < 4; ++i)
#pragma unroll
        for (int j = 0; j < 8; ++j) acc[i][j] = 0.f;

#pragma unroll 4
    for (int k = 0; k < 64; ++k) {
        float z0 = zt[mb + 0][k];
        float z1 = zt[mb + 1][k];
        float z2 = zt[mb + 2][k];
        float z3 = zt[mb + 3][k];
        float4 wa = *reinterpret_cast<const float4*>(sw + k * 64 + c0);
        float4 wb = *reinterpret_cast<const float4*>(sw + k * 64 + c0 + 4);
        float w[8] = {wa.x, wa.y, wa.z, wa.w, wb.x, wb.y, wb.z, wb.w};
#pragma unroll
        for (int j = 0; j < 8; ++j) {
            acc[0][j] += z0 * w[j];
            acc[1][j] += z1 * w[j];
            acc[2][j] += z2 * w[j];
            acc[3][j] += z3 * w[j];
        }
    }

#pragma unroll
    for (int i = 0; i < 4; ++i) {
        int gm = node0 + mb + i;
        if (gm >= n) continue;
        if (cg < 8) {
            uint4 pk;
            pk.x = (unsigned)f2bf(acc[i][0]) | ((unsigned)f2bf(acc[i][1]) << 16);
            pk.y = (unsigned)f2bf(acc[i][2]) | ((unsigned)f2bf(acc[i][3]) << 16);
            pk.z = (unsigned)f2bf(acc[i][4]) | ((unsigned)f2bf(acc[i][5]) << 16);
            pk.w = (unsigned)f2bf(acc[i][6]) | ((unsigned)f2bf(acc[i][7]) << 16);
            *reinterpret_cast<uint4*>(yl + (size_t)gm * 64 + c0) = pk;
        } else {
            float* dp = h + (size_t)gm * 64 + c0;
            *reinterpret_cast<float4*>(dp) =
                make_float4(acc[i][0] + sbl[c0 + 0], acc[i][1] + sbl[c0 + 1],
                            acc[i][2] + sbl[c0 + 2], acc[i][3] + sbl[c0 + 3]);
            *reinterpret_cast<float4*>(dp + 4) =
                make_float4(acc[i][4] + sbl[c0 + 4], acc[i][5] + sbl[c0 + 5],
                            acc[i][6] + sbl[c0 + 6], acc[i][7] + sbl[c0 + 7]);
        }
    }
}

// ---------------- gather: h[i] += mean_j yl[col_j] ----------------
// Wave per node. Lane owns column pair (2c,2c+1) as one dword of 2 bf16.
// Lane halves 0-31 / 32-63 take even/odd neighbors: 8 dword loads = 16 neighbors.

__global__ __launch_bounds__(512) void gather_kernel(
    const ushort* __restrict__ yl, float* __restrict__ h,
    const int* __restrict__ col, const int2* __restrict__ seg, int n)
{
    int lane = threadIdx.x & 63;
    int node = blockIdx.x * 8 + (threadIdx.x >> 6);
    if (node >= n) return;

    int2 sc = seg[node];
    int s0  = __builtin_amdgcn_readfirstlane(sc.x);
    int deg = __builtin_amdgcn_readfirstlane(sc.y);
    int pc  = (deg + 15) & ~15;
    const int* __restrict__ cp = col + s0;

    bool hi = lane >= 32;
    unsigned cl = (unsigned)(lane & 31);          // columns 2cl, 2cl+1
    const unsigned* __restrict__ ylu = reinterpret_cast<const unsigned*>(yl);  // row stride 32

    float alo = 0.f, ahi = 0.f;
    for (int j0 = 0; j0 < pc; j0 += 16) {
        int4 ia = *reinterpret_cast<const int4*>(cp + j0);
        int4 ib = *reinterpret_cast<const int4*>(cp + j0 + 4);
        int4 ic = *reinterpret_cast<const int4*>(cp + j0 + 8);
        int4 id = *reinterpret_cast<const int4*>(cp + j0 + 12);
        unsigned p0 = (unsigned)(hi ? ia.y : ia.x);
        unsigned p1 = (unsigned)(hi ? ia.w : ia.z);
        unsigned p2 = (unsigned)(hi ? ib.y : ib.x);
        unsigned p3 = (unsigned)(hi ? ib.w : ib.z);
        unsigned p4 = (unsigned)(hi ? ic.y : ic.x);
        unsigned p5 = (unsigned)(hi ? ic.w : ic.z);
        unsigned p6 = (unsigned)(hi ? id.y : id.x);
        unsigned p7 = (unsigned)(hi ? id.w : id.z);
        unsigned u0 = ylu[(p0 << 5) + cl];
        unsigned u1 = ylu[(p1 << 5) + cl];
        unsigned u2 = ylu[(p2 << 5) + cl];
        unsigned u3 = ylu[(p3 << 5) + cl];
        unsigned u4 = ylu[(p4 << 5) + cl];
        unsigned u5 = ylu[(p5 << 5) + cl];
        unsigned u6 = ylu[(p6 << 5) + cl];
        unsigned u7 = ylu[(p7 << 5) + cl];
        alo += __uint_as_float(u0 << 16);           ahi += __uint_as_float(u0 & 0xFFFF0000u);
        alo += __uint_as_float(u1 << 16);           ahi += __uint_as_float(u1 & 0xFFFF0000u);
        alo += __uint_as_float(u2 << 16);           ahi += __uint_as_float(u2 & 0xFFFF0000u);
        alo += __uint_as_float(u3 << 16);           ahi += __uint_as_float(u3 & 0xFFFF0000u);
        alo += __uint_as_float(u4 << 16);           ahi += __uint_as_float(u4 & 0xFFFF0000u);
        alo += __uint_as_float(u5 << 16);           ahi += __uint_as_float(u5 & 0xFFFF0000u);
        alo += __uint_as_float(u6 << 16);           ahi += __uint_as_float(u6 & 0xFFFF0000u);
        alo += __uint_as_float(u7 << 16);           ahi += __uint_as_float(u7 & 0xFFFF0000u);
    }
    alo += __shfl_xor(alo, 32);
    ahi += __shfl_xor(ahi, 32);
    if (!hi) {
        float inv = 1.f / (float)max(deg, 1);
        float2* hp = reinterpret_cast<float2*>(h + (size_t)node * 64 + 2 * cl);
        float2 hv = *hp;
        hv.x += alo * inv;
        hv.y += ahi * inv;
        *hp = hv;
    }
}

// ---------------- BN statistics ----------------

__global__ __launch_bounds__(256) void bn_stats(const float* __restrict__ h,
                                                float* __restrict__ sums, int n) {
    __shared__ float ls[128];
    if (threadIdx.x < 128) ls[threadIdx.x] = 0.f;
    __syncthreads();
    size_t total = (size_t)n * 64;
    size_t stride = (size_t)gridDim.x * 1024;
    float s0 = 0.f, s1 = 0.f, s2 = 0.f, s3 = 0.f;
    float q0 = 0.f, q1 = 0.f, q2 = 0.f, q3 = 0.f;
    for (size_t i = (size_t)blockIdx.x * 1024 + (size_t)threadIdx.x * 4; i < total; i += stride) {
        float4 v = *reinterpret_cast<const float4*>(h + i);
        s0 += v.x; q0 += v.x * v.x;
        s1 += v.y; q1 += v.y * v.y;
        s2 += v.z; q2 += v.z * v.z;
        s3 += v.w; q3 += v.w * v.w;
    }
    int c = (threadIdx.x * 4) & 63;
    atomicAdd(&ls[c + 0], s0); atomicAdd(&ls[c + 1], s1);
    atomicAdd(&ls[c + 2], s2); atomicAdd(&ls[c + 3], s3);
    atomicAdd(&ls[64 + c + 0], q0); atomicAdd(&ls[64 + c + 1], q1);
    atomicAdd(&ls[64 + c + 2], q2); atomicAdd(&ls[64 + c + 3], q3);
    __syncthreads();
    if (threadIdx.x < 128) atomicAdd(&sums[threadIdx.x], ls[threadIdx.x]);
}

__global__ void bn_finalize(const float* __restrict__ sums, const float* __restrict__ g,
                            const float* __restrict__ be, float* __restrict__ scale,
                            float* __restrict__ shift, int n) {
    int c = threadIdx.x;
    if (c < 64) {
        float inv_n = 1.f / (float)n;
        float mu = sums[c] * inv_n;
        float var = sums[64 + c] * inv_n - mu * mu;
        float sc = g[c] * rsqrtf(var + EPSV);
        scale[c] = sc;
        shift[c] = be[c] - mu * sc;
    }
}

// ---------------- output head: relu(BN(h)) @ Wo + bo ----------------

__global__ __launch_bounds__(256) void out_kernel(const float* __restrict__ h,
                                                  const float* __restrict__ scale,
                                                  const float* __restrict__ shift,
                                                  const float* __restrict__ Wo,
                                                  const float* __restrict__ bo,
                                                  float* __restrict__ out, int n) {
    int lane = threadIdx.x & 63;
    int wave = threadIdx.x >> 6;
    int node = blockIdx.x * 4 + wave;
    if (node >= n) return;
    float v = h[(size_t)node * 64 + lane];
    v = fmaxf(v * scale[lane] + shift[lane], 0.f);
    float p = v * Wo[lane];
    for (int d = 32; d > 0; d >>= 1) p += __shfl_xor(p, d);
    if (lane == 0) out[node] = p + bo[0];
}

// ---------------- launch ----------------

extern "C" void kernel_launch(void* const* d_in, const int* in_sizes, int n_in,
                              void* d_out, int out_size, void* d_ws, size_t ws_size,
                              hipStream_t stream) {
    const float* x   = (const float*)d_in[0];
    const int*   ei  = (const int*)d_in[1];
    const float* Wl0 = (const float*)d_in[2];
    const float* bl0 = (const float*)d_in[3];
    const float* Wr0 = (const float*)d_in[4];
    const float* g0  = (const float*)d_in[5];
    const float* be0 = (const float*)d_in[6];
    const float* Wl1 = (const float*)d_in[7];
    const float* bl1 = (const float*)d_in[8];
    const float* Wr1 = (const float*)d_in[9];
    const float* g1  = (const float*)d_in[10];
    const float* be1 = (const float*)d_in[11];
    const float* Wl2 = (const float*)d_in[12];
    const float* bl2 = (const float*)d_in[13];
    const float* Wr2 = (const float*)d_in[14];
    const float* g2  = (const float*)d_in[15];
    const float* be2 = (const float*)d_in[16];
    const float* Wo  = (const float*)d_in[17];
    const float* bo  = (const float*)d_in[18];

    const int N = in_sizes[0] / 7;
    const int E = in_sizes[1] / 2;
    const int NB = (N + 63) / 64;
    const int* srcp = ei;
    const int* dstp = ei + E;

    char* ws = (char*)d_ws;
    size_t off = 0;
    auto walloc = [&](size_t bytes) -> void* {
        void* p = ws + off;
        off = (off + bytes + 255) & ~(size_t)255;
        return p;
    };
    int*    bcnt   = (int*)walloc((size_t)NB * 16 * sizeof(int));   // 1 counter per 64B line
    int*    bbuf   = (int*)walloc((size_t)NB * BCAP * sizeof(int));
    int2*   seg    = (int2*)walloc((size_t)N * sizeof(int2));
    int*    col    = (int*)walloc((size_t)NB * CWIN * sizeof(int));
    float*  sums   = (float*)walloc(3 * 128 * sizeof(float));
    float*  scale  = (float*)walloc(3 * 64 * sizeof(float));
    float*  shift  = (float*)walloc(3 * 64 * sizeof(float));
    ushort* yl     = (ushort*)walloc(((size_t)N + 1) * 64 * sizeof(ushort));  // row N = zeros
    float*  h0     = (float*)walloc((size_t)N * 64 * sizeof(float));
    float*  h1     = (float*)walloc((size_t)N * 64 * sizeof(float));

    hipMemsetAsync(bcnt, 0, (size_t)NB * 16 * sizeof(int), stream);
    hipMemsetAsync(sums, 0, 3 * 128 * sizeof(float), stream);

    bucket_scatter<<<(E + 255) / 256, 256, 0, stream>>>(srcp, dstp, bcnt, bbuf, E);
    bucket_build<<<NB, 256, 0, stream>>>(bcnt, bbuf, seg, col, N);

    const int gw = (N + 7) / 8;       // wave-per-node grids (512 threads)
    const int gt = (N + 63) / 64;     // transform64 tiles

    // ---- layer 0 ----
    transform7<<<gw, 512, 0, stream>>>(x, Wl0, bl0, Wr0, yl, h0, N);
    gather_kernel<<<gw, 512, 0, stream>>>(yl, h0, col, seg, N);
    bn_stats<<<1024, 256, 0, stream>>>(h0, sums, N);
    bn_finalize<<<1, 64, 0, stream>>>(sums, g0, be0, scale, shift, N);

    // ---- layer 1 ----
    transform64<<<gt, 256, 0, stream>>>(h0, scale, shift, Wl1, Wr1, bl1, yl, h1, N);
    gather_kernel<<<gw, 512, 0, stream>>>(yl, h1, col, seg, N);
    bn_stats<<<1024, 256, 0, stream>>>(h1, sums + 128, N);
    bn_finalize<<<1, 64, 0, stream>>>(sums + 128, g1, be1, scale + 64, shift + 64, N);

    // ---- layer 2 ----
    transform64<<<gt, 256, 0, stream>>>(h1, scale + 64, shift + 64, Wl2, Wr2, bl2, yl, h0, N);
    gather_kernel<<<gw, 512, 0, stream>>>(yl, h0, col, seg, N);
    bn_stats<<<1024, 256, 0, stream>>>(h0, sums + 256, N);
    bn_finalize<<<1, 64, 0, stream>>>(sums + 256, g2, be2, scale + 128, shift + 128, N);

    out_kernel<<<(N + 3) / 4, 256, 0, stream>>>(h0, scale + 128, shift + 128, Wo, bo, (float*)d_out, N);
}

// Round 8
// 410.345 us; speedup vs baseline: 3.2037x; 1.0996x over previous
//
#include <hip/hip_runtime.h>

#define EPSV 1e-5f
#define REP 8                // bucket counter/window replicas (keyed by blockIdx&7)
#define BCAP_R 224           // per-replica bucket capacity: mean 128, sd 11 -> +8.5 sd
#define CWIN (1280 + 960)    // per-bucket col window: edges (mean 1024 +8sd) + worst-case pad

static __device__ __forceinline__ ushort f2bf(float f) {
    unsigned u = __float_as_uint(f);
    unsigned r = (u + 0x7FFF + ((u >> 16) & 1)) >> 16;   // RTNE
    return (ushort)r;
}

// ---------------- CSR build: bucketed counting sort, 8-way replicated ----------------
// Bucket = 64 consecutive dst ids. Counters are 1-per-64B-line AND replicated
// 8x by blockIdx&7: same-line atomic chains drop from ~1024 to ~128 ops
// (cross-XCD same-line atomics measured ~250cy/op -> was 108us serialization).
// Pass 2: one block per bucket merges the 8 replica sub-lists into the padded
// CSR in a STATIC per-bucket col window (no global cursor). Segments padded to
// multiple of 16 with index n (zero row); inter-window gaps are never read.

__global__ __launch_bounds__(256) void bucket_scatter(
    const int* __restrict__ src, const int* __restrict__ dst,
    int* __restrict__ bcnt, int* __restrict__ bbuf, int E, int NB)
{
    int r = blockIdx.x & (REP - 1);
    int i4 = (blockIdx.x * 256 + threadIdx.x) * 4;
    if (i4 + 3 < E) {
        int4 d4 = *reinterpret_cast<const int4*>(dst + i4);
        int4 s4 = *reinterpret_cast<const int4*>(src + i4);
        int b0 = (r * NB + (d4.x >> 6)) * 16;
        int b1 = (r * NB + (d4.y >> 6)) * 16;
        int b2 = (r * NB + (d4.z >> 6)) * 16;
        int b3 = (r * NB + (d4.w >> 6)) * 16;
        int p0 = atomicAdd(&bcnt[b0], 1);
        int p1 = atomicAdd(&bcnt[b1], 1);
        int p2 = atomicAdd(&bcnt[b2], 1);
        int p3 = atomicAdd(&bcnt[b3], 1);
        if (p0 < BCAP_R) bbuf[(size_t)(b0 >> 4) * BCAP_R + p0] = ((d4.x & 63) << 17) | s4.x;
        if (p1 < BCAP_R) bbuf[(size_t)(b1 >> 4) * BCAP_R + p1] = ((d4.y & 63) << 17) | s4.y;
        if (p2 < BCAP_R) bbuf[(size_t)(b2 >> 4) * BCAP_R + p2] = ((d4.z & 63) << 17) | s4.z;
        if (p3 < BCAP_R) bbuf[(size_t)(b3 >> 4) * BCAP_R + p3] = ((d4.w & 63) << 17) | s4.w;
    } else {
        for (int j = 0; j < 4; ++j) {
            int i = i4 + j;
            if (i < E) {
                int d = dst[i];
                int bi = (r * NB + (d >> 6)) * 16;
                int p = atomicAdd(&bcnt[bi], 1);
                if (p < BCAP_R) bbuf[(size_t)(bi >> 4) * BCAP_R + p] = ((d & 63) << 17) | src[i];
            }
        }
    }
}

__global__ __launch_bounds__(256) void bucket_build(
    const int* __restrict__ bcnt, const int* __restrict__ bbuf,
    int2* __restrict__ seg, int* __restrict__ col, int n, int NB)
{
    __shared__ int lcnt[64], loff[64], lcur[64];
    int b = blockIdx.x;
    int node0 = b << 6;
    int t = threadIdx.x;
    if (t < 64) lcnt[t] = 0;
    __syncthreads();

    for (int r = 0; r < REP; ++r) {
        int cnt = min(bcnt[(r * NB + b) * 16], BCAP_R);
        const int* __restrict__ eb = bbuf + (size_t)(r * NB + b) * BCAP_R;
        for (int i = t; i < cnt; i += 256) atomicAdd(&lcnt[eb[i] >> 17], 1);
    }
    __syncthreads();

    if (t < 64) {                       // wave 0: scan of padded counts
        int pc = (lcnt[t] + 15) & ~15;
        int pre = pc;
        for (int d = 1; d < 64; d <<= 1) {
            int tm = __shfl_up(pre, d);
            if (t >= d) pre += tm;
        }
        loff[t] = pre - pc;
    }
    __syncthreads();
    if (t < 64) {
        int st = b * CWIN + loff[t];
        lcur[t] = st;
        if (node0 + t < n) seg[node0 + t] = make_int2(st, lcnt[t]);
    }
    __syncthreads();

    for (int r = 0; r < REP; ++r) {
        int cnt = min(bcnt[(r * NB + b) * 16], BCAP_R);
        const int* __restrict__ eb = bbuf + (size_t)(r * NB + b) * BCAP_R;
        for (int i = t; i < cnt; i += 256) {
            int e = eb[i];
            int p = atomicAdd(&lcur[e >> 17], 1);
            col[p] = e & 0x1FFFF;
        }
    }
    __syncthreads();
    if (t < 64) {                       // pads -> zero row n
        int st = b * CWIN + loff[t];
        int pend = st + ((lcnt[t] + 15) & ~15);
        for (int p = st + lcnt[t]; p < pend; ++p) col[p] = n;
    }
}

// ---------------- transform, DIN=7: yl = x@Wl (bf16) ; h = x@Wr + bl ----------------

__global__ __launch_bounds__(512) void transform7(
    const float* __restrict__ x,
    const float* __restrict__ Wl, const float* __restrict__ bl, const float* __restrict__ Wr,
    ushort* __restrict__ yl, float* __restrict__ h, int n)
{
    __shared__ float swl[7 * 64], swr[7 * 64], sbl[64];
    for (int i = threadIdx.x; i < 7 * 64; i += 512) { swl[i] = Wl[i]; swr[i] = Wr[i]; }
    if (threadIdx.x < 64) sbl[threadIdx.x] = bl[threadIdx.x];
    __syncthreads();

    if (blockIdx.x == 0 && threadIdx.x < 64) yl[(size_t)n * 64 + threadIdx.x] = 0;  // pad row

    int lane = threadIdx.x & 63;
    int node = blockIdx.x * 8 + (threadIdx.x >> 6);
    if (node >= n) return;

    float xv = (lane < 7) ? x[(size_t)node * 7 + lane] : 0.f;
    float hl = 0.f, hr = sbl[lane];
#pragma unroll
    for (int k = 0; k < 7; ++k) {
        float xk = __shfl(xv, k);
        hl += xk * swl[k * 64 + lane];
        hr += xk * swr[k * 64 + lane];
    }
    yl[(size_t)node * 64 + lane] = f2bf(hl);
    h[(size_t)node * 64 + lane] = hr;
}

// ---------------- transform, DIN=64: z = relu(BN(zin)); yl = z@Wl (bf16); h = z@Wr + bl ----

__global__ __launch_bounds__(256) void transform64(
    const float* __restrict__ zin, const float* __restrict__ scale, const float* __restrict__ shift,
    const float* __restrict__ Wl, const float* __restrict__ Wr, const float* __restrict__ bl,
    ushort* __restrict__ yl, float* __restrict__ h, int n)
{
    __shared__ float zt[64][68];
    __shared__ float swl[64 * 64];
    __shared__ float swr[64 * 64];
    __shared__ float ssc[64], ssh[64], sbl[64];

    int t = threadIdx.x;
    if (t < 64) { ssc[t] = scale[t]; ssh[t] = shift[t]; sbl[t] = bl[t]; }
    for (int i = t; i < 4096; i += 256) { swl[i] = Wl[i]; swr[i] = Wr[i]; }
    __syncthreads();

    int node0 = blockIdx.x * 64;
    {
        int m = t >> 2, c4 = (t & 3) * 16;
        int gm = node0 + m;
        if (gm < n) {
            const float4* zp = reinterpret_cast<const float4*>(zin + (size_t)gm * 64 + c4);
#pragma unroll
            for (int j = 0; j < 4; ++j) {
                float4 v = zp[j];
                int c = c4 + j * 4;
                v.x = fmaxf(v.x * ssc[c + 0] + ssh[c + 0], 0.f);
                v.y = fmaxf(v.y * ssc[c + 1] + ssh[c + 1], 0.f);
                v.z = fmaxf(v.z * ssc[c + 2] + ssh[c + 2], 0.f);
                v.w = fmaxf(v.w * ssc[c + 3] + ssh[c + 3], 0.f);
                zt[m][c + 0] = v.x; zt[m][c + 1] = v.y; zt[m][c + 2] = v.z; zt[m][c + 3] = v.w;
            }
        } else {
#pragma unroll
            for (int j = 0; j < 16; ++j) zt[m][c4 + j] = 0.f;
        }
    }
    __syncthreads();

    int ng = t >> 4;            // nodes ng*4..+3
    int cg = t & 15;            // cg<8 -> Wl (yl out), cg>=8 -> Wr (h out)
    int mb = ng * 4;
    const float* sw = (cg < 8) ? swl : swr;
    int c0 = (cg & 7) * 8;

    float acc[4][8];
#pragma unroll
    for (int i = 0; i < 4; ++i)
#pragma unroll
        for (int j = 0; j < 8; ++j) acc[i][j] = 0.f;

#pragma unroll 4
    for (int k = 0; k < 64; ++k) {
        float z0 = zt[mb + 0][k];
        float z1 = zt[mb + 1][k];
        float z2 = zt[mb + 2][k];
        float z3 = zt[mb + 3][k];
        float4 wa = *reinterpret_cast<const float4*>(sw + k * 64 + c0);
        float4 wb = *reinterpret_cast<const float4*>(sw + k * 64 + c0 + 4);
        float w[8] = {wa.x, wa.y, wa.z, wa.w, wb.x, wb.y, wb.z, wb.w};
#pragma unroll
        for (int j = 0; j < 8; ++j) {
            acc[0][j] += z0 * w[j];
            acc[1][j] += z1 * w[j];
            acc[2][j] += z2 * w[j];
            acc[3][j] += z3 * w[j];
        }
    }

#pragma unroll
    for (int i = 0; i < 4; ++i) {
        int gm = node0 + mb + i;
        if (gm >= n) continue;
        if (cg < 8) {
            uint4 pk;
            pk.x = (unsigned)f2bf(acc[i][0]) | ((unsigned)f2bf(acc[i][1]) << 16);
            pk.y = (unsigned)f2bf(acc[i][2]) | ((unsigned)f2bf(acc[i][3]) << 16);
            pk.z = (unsigned)f2bf(acc[i][4]) | ((unsigned)f2bf(acc[i][5]) << 16);
            pk.w = (unsigned)f2bf(acc[i][6]) | ((unsigned)f2bf(acc[i][7]) << 16);
            *reinterpret_cast<uint4*>(yl + (size_t)gm * 64 + c0) = pk;
        } else {
            float* dp = h + (size_t)gm * 64 + c0;
            *reinterpret_cast<float4*>(dp) =
                make_float4(acc[i][0] + sbl[c0 + 0], acc[i][1] + sbl[c0 + 1],
                            acc[i][2] + sbl[c0 + 2], acc[i][3] + sbl[c0 + 3]);
            *reinterpret_cast<float4*>(dp + 4) =
                make_float4(acc[i][4] + sbl[c0 + 4], acc[i][5] + sbl[c0 + 5],
                            acc[i][6] + sbl[c0 + 6], acc[i][7] + sbl[c0 + 7]);
        }
    }
}

// ---------------- gather: h[i] += mean_j yl[col_j] ----------------
// Wave per node. Lane owns column pair (2c,2c+1) as one dword of 2 bf16.
// Lane halves 0-31 / 32-63 take even/odd neighbors: 8 dword loads = 16 neighbors.

__global__ __launch_bounds__(512) void gather_kernel(
    const ushort* __restrict__ yl, float* __restrict__ h,
    const int* __restrict__ col, const int2* __restrict__ seg, int n)
{
    int lane = threadIdx.x & 63;
    int node = blockIdx.x * 8 + (threadIdx.x >> 6);
    if (node >= n) return;

    int2 sc = seg[node];
    int s0  = __builtin_amdgcn_readfirstlane(sc.x);
    int deg = __builtin_amdgcn_readfirstlane(sc.y);
    int pc  = (deg + 15) & ~15;
    const int* __restrict__ cp = col + s0;

    bool hi = lane >= 32;
    unsigned cl = (unsigned)(lane & 31);          // columns 2cl, 2cl+1
    const unsigned* __restrict__ ylu = reinterpret_cast<const unsigned*>(yl);  // row stride 32

    float alo = 0.f, ahi = 0.f;
    for (int j0 = 0; j0 < pc; j0 += 16) {
        int4 ia = *reinterpret_cast<const int4*>(cp + j0);
        int4 ib = *reinterpret_cast<const int4*>(cp + j0 + 4);
        int4 ic = *reinterpret_cast<const int4*>(cp + j0 + 8);
        int4 id = *reinterpret_cast<const int4*>(cp + j0 + 12);
        unsigned p0 = (unsigned)(hi ? ia.y : ia.x);
        unsigned p1 = (unsigned)(hi ? ia.w : ia.z);
        unsigned p2 = (unsigned)(hi ? ib.y : ib.x);
        unsigned p3 = (unsigned)(hi ? ib.w : ib.z);
        unsigned p4 = (unsigned)(hi ? ic.y : ic.x);
        unsigned p5 = (unsigned)(hi ? ic.w : ic.z);
        unsigned p6 = (unsigned)(hi ? id.y : id.x);
        unsigned p7 = (unsigned)(hi ? id.w : id.z);
        unsigned u0 = ylu[(p0 << 5) + cl];
        unsigned u1 = ylu[(p1 << 5) + cl];
        unsigned u2 = ylu[(p2 << 5) + cl];
        unsigned u3 = ylu[(p3 << 5) + cl];
        unsigned u4 = ylu[(p4 << 5) + cl];
        unsigned u5 = ylu[(p5 << 5) + cl];
        unsigned u6 = ylu[(p6 << 5) + cl];
        unsigned u7 = ylu[(p7 << 5) + cl];
        alo += __uint_as_float(u0 << 16);           ahi += __uint_as_float(u0 & 0xFFFF0000u);
        alo += __uint_as_float(u1 << 16);           ahi += __uint_as_float(u1 & 0xFFFF0000u);
        alo += __uint_as_float(u2 << 16);           ahi += __uint_as_float(u2 & 0xFFFF0000u);
        alo += __uint_as_float(u3 << 16);           ahi += __uint_as_float(u3 & 0xFFFF0000u);
        alo += __uint_as_float(u4 << 16);           ahi += __uint_as_float(u4 & 0xFFFF0000u);
        alo += __uint_as_float(u5 << 16);           ahi += __uint_as_float(u5 & 0xFFFF0000u);
        alo += __uint_as_float(u6 << 16);           ahi += __uint_as_float(u6 & 0xFFFF0000u);
        alo += __uint_as_float(u7 << 16);           ahi += __uint_as_float(u7 & 0xFFFF0000u);
    }
    alo += __shfl_xor(alo, 32);
    ahi += __shfl_xor(ahi, 32);
    if (!hi) {
        float inv = 1.f / (float)max(deg, 1);
        float2* hp = reinterpret_cast<float2*>(h + (size_t)node * 64 + 2 * cl);
        float2 hv = *hp;
        hv.x += alo * inv;
        hv.y += ahi * inv;
        *hp = hv;
    }
}

// ---------------- BN statistics ----------------

__global__ __launch_bounds__(256) void bn_stats(const float* __restrict__ h,
                                                float* __restrict__ sums, int n) {
    __shared__ float ls[128];
    if (threadIdx.x < 128) ls[threadIdx.x] = 0.f;
    __syncthreads();
    size_t total = (size_t)n * 64;
    size_t stride = (size_t)gridDim.x * 1024;
    float s0 = 0.f, s1 = 0.f, s2 = 0.f, s3 = 0.f;
    float q0 = 0.f, q1 = 0.f, q2 = 0.f, q3 = 0.f;
    for (size_t i = (size_t)blockIdx.x * 1024 + (size_t)threadIdx.x * 4; i < total; i += stride) {
        float4 v = *reinterpret_cast<const float4*>(h + i);
        s0 += v.x; q0 += v.x * v.x;
        s1 += v.y; q1 += v.y * v.y;
        s2 += v.z; q2 += v.z * v.z;
        s3 += v.w; q3 += v.w * v.w;
    }
    int c = (threadIdx.x * 4) & 63;
    atomicAdd(&ls[c + 0], s0); atomicAdd(&ls[c + 1], s1);
    atomicAdd(&ls[c + 2], s2); atomicAdd(&ls[c + 3], s3);
    atomicAdd(&ls[64 + c + 0], q0); atomicAdd(&ls[64 + c + 1], q1);
    atomicAdd(&ls[64 + c + 2], q2); atomicAdd(&ls[64 + c + 3], q3);
    __syncthreads();
    if (threadIdx.x < 128) atomicAdd(&sums[threadIdx.x], ls[threadIdx.x]);
}

__global__ void bn_finalize(const float* __restrict__ sums, const float* __restrict__ g,
                            const float* __restrict__ be, float* __restrict__ scale,
                            float* __restrict__ shift, int n) {
    int c = threadIdx.x;
    if (c < 64) {
        float inv_n = 1.f / (float)n;
        float mu = sums[c] * inv_n;
        float var = sums[64 + c] * inv_n - mu * mu;
        float sc = g[c] * rsqrtf(var + EPSV);
        scale[c] = sc;
        shift[c] = be[c] - mu * sc;
    }
}

// ---------------- output head: relu(BN(h)) @ Wo + bo ----------------

__global__ __launch_bounds__(256) void out_kernel(const float* __restrict__ h,
                                                  const float* __restrict__ scale,
                                                  const float* __restrict__ shift,
                                                  const float* __restrict__ Wo,
                                                  const float* __restrict__ bo,
                                                  float* __restrict__ out, int n) {
    int lane = threadIdx.x & 63;
    int wave = threadIdx.x >> 6;
    int node = blockIdx.x * 4 + wave;
    if (node >= n) return;
    float v = h[(size_t)node * 64 + lane];
    v = fmaxf(v * scale[lane] + shift[lane], 0.f);
    float p = v * Wo[lane];
    for (int d = 32; d > 0; d >>= 1) p += __shfl_xor(p, d);
    if (lane == 0) out[node] = p + bo[0];
}

// ---------------- launch ----------------

extern "C" void kernel_launch(void* const* d_in, const int* in_sizes, int n_in,
                              void* d_out, int out_size, void* d_ws, size_t ws_size,
                              hipStream_t stream) {
    const float* x   = (const float*)d_in[0];
    const int*   ei  = (const int*)d_in[1];
    const float* Wl0 = (const float*)d_in[2];
    const float* bl0 = (const float*)d_in[3];
    const float* Wr0 = (const float*)d_in[4];
    const float* g0  = (const float*)d_in[5];
    const float* be0 = (const float*)d_in[6];
    const float* Wl1 = (const float*)d_in[7];
    const float* bl1 = (const float*)d_in[8];
    const float* Wr1 = (const float*)d_in[9];
    const float* g1  = (const float*)d_in[10];
    const float* be1 = (const float*)d_in[11];
    const float* Wl2 = (const float*)d_in[12];
    const float* bl2 = (const float*)d_in[13];
    const float* Wr2 = (const float*)d_in[14];
    const float* g2  = (const float*)d_in[15];
    const float* be2 = (const float*)d_in[16];
    const float* Wo  = (const float*)d_in[17];
    const float* bo  = (const float*)d_in[18];

    const int N = in_sizes[0] / 7;
    const int E = in_sizes[1] / 2;
    const int NB = (N + 63) / 64;
    const int* srcp = ei;
    const int* dstp = ei + E;

    char* ws = (char*)d_ws;
    size_t off = 0;
    auto walloc = [&](size_t bytes) -> void* {
        void* p = ws + off;
        off = (off + bytes + 255) & ~(size_t)255;
        return p;
    };
    int*    bcnt   = (int*)walloc((size_t)REP * NB * 16 * sizeof(int));  // 1 counter per 64B line
    int*    bbuf   = (int*)walloc((size_t)REP * NB * BCAP_R * sizeof(int));
    int2*   seg    = (int2*)walloc((size_t)N * sizeof(int2));
    int*    col    = (int*)walloc((size_t)NB * CWIN * sizeof(int));
    float*  sums   = (float*)walloc(3 * 128 * sizeof(float));
    float*  scale  = (float*)walloc(3 * 64 * sizeof(float));
    float*  shift  = (float*)walloc(3 * 64 * sizeof(float));
    ushort* yl     = (ushort*)walloc(((size_t)N + 1) * 64 * sizeof(ushort));  // row N = zeros
    float*  h0     = (float*)walloc((size_t)N * 64 * sizeof(float));
    float*  h1     = (float*)walloc((size_t)N * 64 * sizeof(float));

    hipMemsetAsync(bcnt, 0, (size_t)REP * NB * 16 * sizeof(int), stream);
    hipMemsetAsync(sums, 0, 3 * 128 * sizeof(float), stream);

    bucket_scatter<<<(E + 1023) / 1024, 256, 0, stream>>>(srcp, dstp, bcnt, bbuf, E, NB);
    bucket_build<<<NB, 256, 0, stream>>>(bcnt, bbuf, seg, col, N, NB);

    const int gw = (N + 7) / 8;       // wave-per-node grids (512 threads)
    const int gt = (N + 63) / 64;     // transform64 tiles

    // ---- layer 0 ----
    transform7<<<gw, 512, 0, stream>>>(x, Wl0, bl0, Wr0, yl, h0, N);
    gather_kernel<<<gw, 512, 0, stream>>>(yl, h0, col, seg, N);
    bn_stats<<<1024, 256, 0, stream>>>(h0, sums, N);
    bn_finalize<<<1, 64, 0, stream>>>(sums, g0, be0, scale, shift, N);

    // ---- layer 1 ----
    transform64<<<gt, 256, 0, stream>>>(h0, scale, shift, Wl1, Wr1, bl1, yl, h1, N);
    gather_kernel<<<gw, 512, 0, stream>>>(yl, h1, col, seg, N);
    bn_stats<<<1024, 256, 0, stream>>>(h1, sums + 128, N);
    bn_finalize<<<1, 64, 0, stream>>>(sums + 128, g1, be1, scale + 64, shift + 64, N);

    // ---- layer 2 ----
    transform64<<<gt, 256, 0, stream>>>(h1, scale + 64, shift + 64, Wl2, Wr2, bl2, yl, h0, N);
    gather_kernel<<<gw, 512, 0, stream>>>(yl, h0, col, seg, N);
    bn_stats<<<1024, 256, 0, stream>>>(h0, sums + 256, N);
    bn_finalize<<<1, 64, 0, stream>>>(sums + 256, g2, be2, scale + 128, shift + 128, N);

    out_kernel<<<(N + 3) / 4, 256, 0, stream>>>(h0, scale + 128, shift + 128, Wo, bo, (float*)d_out, N);
}

// Round 9
// 357.560 us; speedup vs baseline: 3.6766x; 1.1476x over previous
//
#include <hip/hip_runtime.h>

#define EPSV 1e-5f
#define REP 8                // replica count for superbucket counters (keyed blockIdx&7)
#define SBCAP 1280           // per-(replica,superbucket) window: mean 1024, sd 32 -> +8 sd
#define CWIN 16640           // per-superbucket col window: 8192 edges +8sd + pads (512*15), rounded

static __device__ __forceinline__ ushort f2bf(float f) {
    unsigned u = __float_as_uint(f);
    unsigned r = (u + 0x7FFF + ((u >> 16) & 1)) >> 16;   // RTNE
    return (ushort)r;
}

// ---------------- CSR build: super-bucket counting sort ----------------
// Superbucket = 512 consecutive dst ids (NSB ~ 196). Pass 1: per 2048-edge
// block, LDS histogram over NSB counters (LDS-atomic rank per edge), ONE
// global atomic per (block, nonzero sb) -> ~150K global atomics total (was
// 1.6M; scattered-atomic op rate was the 70us limiter), then direct stores at
// base+rank (consecutive ranks per block -> ~40B runs). Pass 2: one block per
// superbucket merges the 8 replica windows: LDS 512-counter histogram,
// wave-scan of padded counts, in-window scatter, pads -> zero row n.

__global__ __launch_bounds__(256) void sb_scatter(
    const int* __restrict__ src, const int* __restrict__ dst,
    int* __restrict__ sbcnt, int* __restrict__ bbuf, int E, int NSB)
{
    __shared__ int hist[512];
    __shared__ int gbase[512];
    int t = threadIdx.x;
    int r = blockIdx.x & (REP - 1);
    for (int i = t; i < NSB; i += 256) hist[i] = 0;
    __syncthreads();

    int base_i = (blockIdx.x * 256 + t) * 8;
    int d[8], s[8], rk[8];
    int m = E - base_i; m = m < 0 ? 0 : (m > 8 ? 8 : m);
    if (m == 8) {
        int4 da = *reinterpret_cast<const int4*>(dst + base_i);
        int4 db = *reinterpret_cast<const int4*>(dst + base_i + 4);
        int4 sa = *reinterpret_cast<const int4*>(src + base_i);
        int4 sb4 = *reinterpret_cast<const int4*>(src + base_i + 4);
        d[0] = da.x; d[1] = da.y; d[2] = da.z; d[3] = da.w;
        d[4] = db.x; d[5] = db.y; d[6] = db.z; d[7] = db.w;
        s[0] = sa.x; s[1] = sa.y; s[2] = sa.z; s[3] = sa.w;
        s[4] = sb4.x; s[5] = sb4.y; s[6] = sb4.z; s[7] = sb4.w;
    } else {
        for (int k = 0; k < m; ++k) { d[k] = dst[base_i + k]; s[k] = src[base_i + k]; }
    }
    for (int k = 0; k < m; ++k)
        rk[k] = atomicAdd(&hist[d[k] >> 9], 1);
    __syncthreads();

    for (int i = t; i < NSB; i += 256) {
        int c = hist[i];
        gbase[i] = c ? atomicAdd(&sbcnt[(r * NSB + i) * 16], c) : 0;
    }
    __syncthreads();

    for (int k = 0; k < m; ++k) {
        int sbk = d[k] >> 9;
        int pos = gbase[sbk] + rk[k];
        if (pos < SBCAP)
            bbuf[(size_t)(r * NSB + sbk) * SBCAP + pos] = ((d[k] & 511) << 17) | s[k];
    }
}

__global__ __launch_bounds__(512) void sb_build(
    const int* __restrict__ sbcnt, const int* __restrict__ bbuf,
    int2* __restrict__ seg, int* __restrict__ col, int n, int NSB)
{
    __shared__ int cnt[512], off[512], cur[512];
    int sb = blockIdx.x;
    int node0 = sb << 9;
    int t = threadIdx.x;
    cnt[t] = 0;
    __syncthreads();

    for (int r = 0; r < REP; ++r) {
        int c = min(sbcnt[(r * NSB + sb) * 16], SBCAP);
        const int* __restrict__ w = bbuf + (size_t)(r * NSB + sb) * SBCAP;
        for (int i = t; i < c; i += 512) atomicAdd(&cnt[w[i] >> 17], 1);
    }
    __syncthreads();

    if (t < 64) {                       // wave 0: scan of padded counts (8/lane)
        int v[8]; int run = 0;
#pragma unroll
        for (int k = 0; k < 8; ++k) {
            v[k] = run;
            run += (cnt[t * 8 + k] + 15) & ~15;
        }
        int pre = run;
        for (int dd = 1; dd < 64; dd <<= 1) {
            int tm = __shfl_up(pre, dd);
            if (t >= dd) pre += tm;
        }
        int lane_excl = pre - run;
#pragma unroll
        for (int k = 0; k < 8; ++k) off[t * 8 + k] = lane_excl + v[k];
    }
    __syncthreads();

    int colbase = sb * CWIN;
    {
        int node = node0 + t;
        if (node < n) seg[node] = make_int2(colbase + off[t], cnt[t]);
        cur[t] = off[t];
    }
    __syncthreads();

    for (int r = 0; r < REP; ++r) {
        int c = min(sbcnt[(r * NSB + sb) * 16], SBCAP);
        const int* __restrict__ w = bbuf + (size_t)(r * NSB + sb) * SBCAP;
        for (int i = t; i < c; i += 512) {
            int e = w[i];
            int p = atomicAdd(&cur[e >> 17], 1);
            col[colbase + p] = e & 0x1FFFF;
        }
    }
    __syncthreads();
    {
        int pend = off[t] + ((cnt[t] + 15) & ~15);
        for (int p = off[t] + cnt[t]; p < pend; ++p) col[colbase + p] = n;
    }
}

// ---------------- transform, DIN=7: yl = x@Wl (bf16) ; h = x@Wr + bl ----------------

__global__ __launch_bounds__(512) void transform7(
    const float* __restrict__ x,
    const float* __restrict__ Wl, const float* __restrict__ bl, const float* __restrict__ Wr,
    ushort* __restrict__ yl, float* __restrict__ h, int n)
{
    __shared__ float swl[7 * 64], swr[7 * 64], sbl[64];
    for (int i = threadIdx.x; i < 7 * 64; i += 512) { swl[i] = Wl[i]; swr[i] = Wr[i]; }
    if (threadIdx.x < 64) sbl[threadIdx.x] = bl[threadIdx.x];
    __syncthreads();

    if (blockIdx.x == 0 && threadIdx.x < 64) yl[(size_t)n * 64 + threadIdx.x] = 0;  // pad row

    int lane = threadIdx.x & 63;
    int node = blockIdx.x * 8 + (threadIdx.x >> 6);
    if (node >= n) return;

    float xv = (lane < 7) ? x[(size_t)node * 7 + lane] : 0.f;
    float hl = 0.f, hr = sbl[lane];
#pragma unroll
    for (int k = 0; k < 7; ++k) {
        float xk = __shfl(xv, k);
        hl += xk * swl[k * 64 + lane];
        hr += xk * swr[k * 64 + lane];
    }
    yl[(size_t)node * 64 + lane] = f2bf(hl);
    h[(size_t)node * 64 + lane] = hr;
}

// ---------------- transform, DIN=64: z = relu(BN(zin)); yl = z@Wl (bf16); h = z@Wr + bl ----

__global__ __launch_bounds__(256) void transform64(
    const float* __restrict__ zin, const float* __restrict__ scale, const float* __restrict__ shift,
    const float* __restrict__ Wl, const float* __restrict__ Wr, const float* __restrict__ bl,
    ushort* __restrict__ yl, float* __restrict__ h, int n)
{
    __shared__ float zt[64][68];
    __shared__ float swl[64 * 64];
    __shared__ float swr[64 * 64];
    __shared__ float ssc[64], ssh[64], sbl[64];

    int t = threadIdx.x;
    if (t < 64) { ssc[t] = scale[t]; ssh[t] = shift[t]; sbl[t] = bl[t]; }
    for (int i = t; i < 4096; i += 256) { swl[i] = Wl[i]; swr[i] = Wr[i]; }
    __syncthreads();

    int node0 = blockIdx.x * 64;
    {
        int m = t >> 2, c4 = (t & 3) * 16;
        int gm = node0 + m;
        if (gm < n) {
            const float4* zp = reinterpret_cast<const float4*>(zin + (size_t)gm * 64 + c4);
#pragma unroll
            for (int j = 0; j < 4; ++j) {
                float4 v = zp[j];
                int c = c4 + j * 4;
                v.x = fmaxf(v.x * ssc[c + 0] + ssh[c + 0], 0.f);
                v.y = fmaxf(v.y * ssc[c + 1] + ssh[c + 1], 0.f);
                v.z = fmaxf(v.z * ssc[c + 2] + ssh[c + 2], 0.f);
                v.w = fmaxf(v.w * ssc[c + 3] + ssh[c + 3], 0.f);
                zt[m][c + 0] = v.x; zt[m][c + 1] = v.y; zt[m][c + 2] = v.z; zt[m][c + 3] = v.w;
            }
        } else {
#pragma unroll
            for (int j = 0; j < 16; ++j) zt[m][c4 + j] = 0.f;
        }
    }
    __syncthreads();

    int ng = t >> 4;            // nodes ng*4..+3
    int cg = t & 15;            // cg<8 -> Wl (yl out), cg>=8 -> Wr (h out)
    int mb = ng * 4;
    const float* sw = (cg < 8) ? swl : swr;
    int c0 = (cg & 7) * 8;

    float acc[4][8];
#pragma unroll
    for (int i = 0; i < 4; ++i)
#pragma unroll
        for (int j = 0; j < 8; ++j) acc[i][j] = 0.f;

#pragma unroll 4
    for (int k = 0; k < 64; ++k) {
        float z0 = zt[mb + 0][k];
        float z1 = zt[mb + 1][k];
        float z2 = zt[mb + 2][k];
        float z3 = zt[mb + 3][k];
        float4 wa = *reinterpret_cast<const float4*>(sw + k * 64 + c0);
        float4 wb = *reinterpret_cast<const float4*>(sw + k * 64 + c0 + 4);
        float w[8] = {wa.x, wa.y, wa.z, wa.w, wb.x, wb.y, wb.z, wb.w};
#pragma unroll
        for (int j = 0; j < 8; ++j) {
            acc[0][j] += z0 * w[j];
            acc[1][j] += z1 * w[j];
            acc[2][j] += z2 * w[j];
            acc[3][j] += z3 * w[j];
        }
    }

#pragma unroll
    for (int i = 0; i < 4; ++i) {
        int gm = node0 + mb + i;
        if (gm >= n) continue;
        if (cg < 8) {
            uint4 pk;
            pk.x = (unsigned)f2bf(acc[i][0]) | ((unsigned)f2bf(acc[i][1]) << 16);
            pk.y = (unsigned)f2bf(acc[i][2]) | ((unsigned)f2bf(acc[i][3]) << 16);
            pk.z = (unsigned)f2bf(acc[i][4]) | ((unsigned)f2bf(acc[i][5]) << 16);
            pk.w = (unsigned)f2bf(acc[i][6]) | ((unsigned)f2bf(acc[i][7]) << 16);
            *reinterpret_cast<uint4*>(yl + (size_t)gm * 64 + c0) = pk;
        } else {
            float* dp = h + (size_t)gm * 64 + c0;
            *reinterpret_cast<float4*>(dp) =
                make_float4(acc[i][0] + sbl[c0 + 0], acc[i][1] + sbl[c0 + 1],
                            acc[i][2] + sbl[c0 + 2], acc[i][3] + sbl[c0 + 3]);
            *reinterpret_cast<float4*>(dp + 4) =
                make_float4(acc[i][4] + sbl[c0 + 4], acc[i][5] + sbl[c0 + 5],
                            acc[i][6] + sbl[c0 + 6], acc[i][7] + sbl[c0 + 7]);
        }
    }
}

// ---------------- gather: h[i] += mean_j yl[col_j], 2 nodes per wave ----------------
// Lane owns column pair (2c,2c+1) as one dword of 2 bf16; lane halves take
// even/odd neighbors. Two nodes' load chains interleaved for 2x MLP; epilogue:
// lo lanes RMW node0, hi lanes RMW node1.

__global__ __launch_bounds__(512) void gather_kernel(
    const ushort* __restrict__ yl, float* __restrict__ h,
    const int* __restrict__ col, const int2* __restrict__ seg, int n)
{
    int lane = threadIdx.x & 63;
    int node0 = blockIdx.x * 16 + (threadIdx.x >> 6) * 2;
    if (node0 >= n) return;
    int node1 = node0 + 1;

    int4 sp = *reinterpret_cast<const int4*>(&seg[node0]);   // node0 even -> aligned
    int s0 = __builtin_amdgcn_readfirstlane(sp.x);
    int d0 = __builtin_amdgcn_readfirstlane(sp.y);
    int s1 = __builtin_amdgcn_readfirstlane(sp.z);
    int d1 = __builtin_amdgcn_readfirstlane(sp.w);
    if (node1 >= n) d1 = 0;
    int pc0 = (d0 + 15) & ~15;
    int pc1 = (d1 + 15) & ~15;
    int pcm = max(pc0, pc1);
    const int* __restrict__ cp0 = col + s0;
    const int* __restrict__ cp1 = col + s1;

    bool hi = lane >= 32;
    unsigned cl = (unsigned)(lane & 31);          // columns 2cl, 2cl+1
    const unsigned* __restrict__ ylu = reinterpret_cast<const unsigned*>(yl);  // row stride 32

    float alo0 = 0.f, ahi0 = 0.f, alo1 = 0.f, ahi1 = 0.f;
    for (int j0 = 0; j0 < pcm; j0 += 16) {
        if (j0 < pc0) {
            int4 ia = *reinterpret_cast<const int4*>(cp0 + j0);
            int4 ib = *reinterpret_cast<const int4*>(cp0 + j0 + 4);
            int4 ic = *reinterpret_cast<const int4*>(cp0 + j0 + 8);
            int4 id = *reinterpret_cast<const int4*>(cp0 + j0 + 12);
            unsigned p0 = (unsigned)(hi ? ia.y : ia.x);
            unsigned p1 = (unsigned)(hi ? ia.w : ia.z);
            unsigned p2 = (unsigned)(hi ? ib.y : ib.x);
            unsigned p3 = (unsigned)(hi ? ib.w : ib.z);
            unsigned p4 = (unsigned)(hi ? ic.y : ic.x);
            unsigned p5 = (unsigned)(hi ? ic.w : ic.z);
            unsigned p6 = (unsigned)(hi ? id.y : id.x);
            unsigned p7 = (unsigned)(hi ? id.w : id.z);
            unsigned u0 = ylu[(p0 << 5) + cl];
            unsigned u1 = ylu[(p1 << 5) + cl];
            unsigned u2 = ylu[(p2 << 5) + cl];
            unsigned u3 = ylu[(p3 << 5) + cl];
            unsigned u4 = ylu[(p4 << 5) + cl];
            unsigned u5 = ylu[(p5 << 5) + cl];
            unsigned u6 = ylu[(p6 << 5) + cl];
            unsigned u7 = ylu[(p7 << 5) + cl];
            alo0 += __uint_as_float(u0 << 16);      ahi0 += __uint_as_float(u0 & 0xFFFF0000u);
            alo0 += __uint_as_float(u1 << 16);      ahi0 += __uint_as_float(u1 & 0xFFFF0000u);
            alo0 += __uint_as_float(u2 << 16);      ahi0 += __uint_as_float(u2 & 0xFFFF0000u);
            alo0 += __uint_as_float(u3 << 16);      ahi0 += __uint_as_float(u3 & 0xFFFF0000u);
            alo0 += __uint_as_float(u4 << 16);      ahi0 += __uint_as_float(u4 & 0xFFFF0000u);
            alo0 += __uint_as_float(u5 << 16);      ahi0 += __uint_as_float(u5 & 0xFFFF0000u);
            alo0 += __uint_as_float(u6 << 16);      ahi0 += __uint_as_float(u6 & 0xFFFF0000u);
            alo0 += __uint_as_float(u7 << 16);      ahi0 += __uint_as_float(u7 & 0xFFFF0000u);
        }
        if (j0 < pc1) {
            int4 ia = *reinterpret_cast<const int4*>(cp1 + j0);
            int4 ib = *reinterpret_cast<const int4*>(cp1 + j0 + 4);
            int4 ic = *reinterpret_cast<const int4*>(cp1 + j0 + 8);
            int4 id = *reinterpret_cast<const int4*>(cp1 + j0 + 12);
            unsigned p0 = (unsigned)(hi ? ia.y : ia.x);
            unsigned p1 = (unsigned)(hi ? ia.w : ia.z);
            unsigned p2 = (unsigned)(hi ? ib.y : ib.x);
            unsigned p3 = (unsigned)(hi ? ib.w : ib.z);
            unsigned p4 = (unsigned)(hi ? ic.y : ic.x);
            unsigned p5 = (unsigned)(hi ? ic.w : ic.z);
            unsigned p6 = (unsigned)(hi ? id.y : id.x);
            unsigned p7 = (unsigned)(hi ? id.w : id.z);
            unsigned u0 = ylu[(p0 << 5) + cl];
            unsigned u1 = ylu[(p1 << 5) + cl];
            unsigned u2 = ylu[(p2 << 5) + cl];
            unsigned u3 = ylu[(p3 << 5) + cl];
            unsigned u4 = ylu[(p4 << 5) + cl];
            unsigned u5 = ylu[(p5 << 5) + cl];
            unsigned u6 = ylu[(p6 << 5) + cl];
            unsigned u7 = ylu[(p7 << 5) + cl];
            alo1 += __uint_as_float(u0 << 16);      ahi1 += __uint_as_float(u0 & 0xFFFF0000u);
            alo1 += __uint_as_float(u1 << 16);      ahi1 += __uint_as_float(u1 & 0xFFFF0000u);
            alo1 += __uint_as_float(u2 << 16);      ahi1 += __uint_as_float(u2 & 0xFFFF0000u);
            alo1 += __uint_as_float(u3 << 16);      ahi1 += __uint_as_float(u3 & 0xFFFF0000u);
            alo1 += __uint_as_float(u4 << 16);      ahi1 += __uint_as_float(u4 & 0xFFFF0000u);
            alo1 += __uint_as_float(u5 << 16);      ahi1 += __uint_as_float(u5 & 0xFFFF0000u);
            alo1 += __uint_as_float(u6 << 16);      ahi1 += __uint_as_float(u6 & 0xFFFF0000u);
            alo1 += __uint_as_float(u7 << 16);      ahi1 += __uint_as_float(u7 & 0xFFFF0000u);
        }
    }
    alo0 += __shfl_xor(alo0, 32);
    ahi0 += __shfl_xor(ahi0, 32);
    alo1 += __shfl_xor(alo1, 32);
    ahi1 += __shfl_xor(ahi1, 32);

    int mynode = hi ? node1 : node0;
    int mydeg  = hi ? d1 : d0;
    float a    = hi ? alo1 : alo0;
    float b    = hi ? ahi1 : ahi0;
    if (mynode < n) {
        float inv = 1.f / (float)max(mydeg, 1);
        float2* hp = reinterpret_cast<float2*>(h + (size_t)mynode * 64 + 2 * cl);
        float2 hv = *hp;
        hv.x += a * inv;
        hv.y += b * inv;
        *hp = hv;
    }
}

// ---------------- BN statistics ----------------

__global__ __launch_bounds__(256) void bn_stats(const float* __restrict__ h,
                                                float* __restrict__ sums, int n) {
    __shared__ float ls[128];
    if (threadIdx.x < 128) ls[threadIdx.x] = 0.f;
    __syncthreads();
    size_t total = (size_t)n * 64;
    size_t stride = (size_t)gridDim.x * 1024;
    float s0 = 0.f, s1 = 0.f, s2 = 0.f, s3 = 0.f;
    float q0 = 0.f, q1 = 0.f, q2 = 0.f, q3 = 0.f;
    for (size_t i = (size_t)blockIdx.x * 1024 + (size_t)threadIdx.x * 4; i < total; i += stride) {
        float4 v = *reinterpret_cast<const float4*>(h + i);
        s0 += v.x; q0 += v.x * v.x;
        s1 += v.y; q1 += v.y * v.y;
        s2 += v.z; q2 += v.z * v.z;
        s3 += v.w; q3 += v.w * v.w;
    }
    int c = (threadIdx.x * 4) & 63;
    atomicAdd(&ls[c + 0], s0); atomicAdd(&ls[c + 1], s1);
    atomicAdd(&ls[c + 2], s2); atomicAdd(&ls[c + 3], s3);
    atomicAdd(&ls[64 + c + 0], q0); atomicAdd(&ls[64 + c + 1], q1);
    atomicAdd(&ls[64 + c + 2], q2); atomicAdd(&ls[64 + c + 3], q3);
    __syncthreads();
    if (threadIdx.x < 128) atomicAdd(&sums[threadIdx.x], ls[threadIdx.x]);
}

__global__ void bn_finalize(const float* __restrict__ sums, const float* __restrict__ g,
                            const float* __restrict__ be, float* __restrict__ scale,
                            float* __restrict__ shift, int n) {
    int c = threadIdx.x;
    if (c < 64) {
        float inv_n = 1.f / (float)n;
        float mu = sums[c] * inv_n;
        float var = sums[64 + c] * inv_n - mu * mu;
        float sc = g[c] * rsqrtf(var + EPSV);
        scale[c] = sc;
        shift[c] = be[c] - mu * sc;
    }
}

// ---------------- output head: relu(BN(h)) @ Wo + bo ----------------

__global__ __launch_bounds__(256) void out_kernel(const float* __restrict__ h,
                                                  const float* __restrict__ scale,
                                                  const float* __restrict__ shift,
                                                  const float* __restrict__ Wo,
                                                  const float* __restrict__ bo,
                                                  float* __restrict__ out, int n) {
    int lane = threadIdx.x & 63;
    int wave = threadIdx.x >> 6;
    int node = blockIdx.x * 4 + wave;
    if (node >= n) return;
    float v = h[(size_t)node * 64 + lane];
    v = fmaxf(v * scale[lane] + shift[lane], 0.f);
    float p = v * Wo[lane];
    for (int d = 32; d > 0; d >>= 1) p += __shfl_xor(p, d);
    if (lane == 0) out[node] = p + bo[0];
}

// ---------------- launch ----------------

extern "C" void kernel_launch(void* const* d_in, const int* in_sizes, int n_in,
                              void* d_out, int out_size, void* d_ws, size_t ws_size,
                              hipStream_t stream) {
    const float* x   = (const float*)d_in[0];
    const int*   ei  = (const int*)d_in[1];
    const float* Wl0 = (const float*)d_in[2];
    const float* bl0 = (const float*)d_in[3];
    const float* Wr0 = (const float*)d_in[4];
    const float* g0  = (const float*)d_in[5];
    const float* be0 = (const float*)d_in[6];
    const float* Wl1 = (const float*)d_in[7];
    const float* bl1 = (const float*)d_in[8];
    const float* Wr1 = (const float*)d_in[9];
    const float* g1  = (const float*)d_in[10];
    const float* be1 = (const float*)d_in[11];
    const float* Wl2 = (const float*)d_in[12];
    const float* bl2 = (const float*)d_in[13];
    const float* Wr2 = (const float*)d_in[14];
    const float* g2  = (const float*)d_in[15];
    const float* be2 = (const float*)d_in[16];
    const float* Wo  = (const float*)d_in[17];
    const float* bo  = (const float*)d_in[18];

    const int N = in_sizes[0] / 7;
    const int E = in_sizes[1] / 2;
    const int NSB = (N + 511) / 512;
    const int* srcp = ei;
    const int* dstp = ei + E;

    char* ws = (char*)d_ws;
    size_t off = 0;
    auto walloc = [&](size_t bytes) -> void* {
        void* p = ws + off;
        off = (off + bytes + 255) & ~(size_t)255;
        return p;
    };
    int*    sbcnt  = (int*)walloc((size_t)REP * NSB * 16 * sizeof(int));  // 1 counter per 64B line
    int*    bbuf   = (int*)walloc((size_t)REP * NSB * SBCAP * sizeof(int));
    int2*   seg    = (int2*)walloc((size_t)(N + 1) * sizeof(int2));
    int*    col    = (int*)walloc((size_t)NSB * CWIN * sizeof(int));
    float*  sums   = (float*)walloc(3 * 128 * sizeof(float));
    float*  scale  = (float*)walloc(3 * 64 * sizeof(float));
    float*  shift  = (float*)walloc(3 * 64 * sizeof(float));
    ushort* yl     = (ushort*)walloc(((size_t)N + 1) * 64 * sizeof(ushort));  // row N = zeros
    float*  h0     = (float*)walloc((size_t)N * 64 * sizeof(float));
    float*  h1     = (float*)walloc((size_t)N * 64 * sizeof(float));

    hipMemsetAsync(sbcnt, 0, (size_t)REP * NSB * 16 * sizeof(int), stream);
    hipMemsetAsync(sums, 0, 3 * 128 * sizeof(float), stream);

    sb_scatter<<<(E + 2047) / 2048, 256, 0, stream>>>(srcp, dstp, sbcnt, bbuf, E, NSB);
    sb_build<<<NSB, 512, 0, stream>>>(sbcnt, bbuf, seg, col, N, NSB);

    const int gw  = (N + 7) / 8;      // wave-per-node grids (512 threads)
    const int gw2 = (N + 15) / 16;    // 2-node-per-wave gather grid
    const int gt  = (N + 63) / 64;    // transform64 tiles

    // ---- layer 0 ----
    transform7<<<gw, 512, 0, stream>>>(x, Wl0, bl0, Wr0, yl, h0, N);
    gather_kernel<<<gw2, 512, 0, stream>>>(yl, h0, col, seg, N);
    bn_stats<<<1024, 256, 0, stream>>>(h0, sums, N);
    bn_finalize<<<1, 64, 0, stream>>>(sums, g0, be0, scale, shift, N);

    // ---- layer 1 ----
    transform64<<<gt, 256, 0, stream>>>(h0, scale, shift, Wl1, Wr1, bl1, yl, h1, N);
    gather_kernel<<<gw2, 512, 0, stream>>>(yl, h1, col, seg, N);
    bn_stats<<<1024, 256, 0, stream>>>(h1, sums + 128, N);
    bn_finalize<<<1, 64, 0, stream>>>(sums + 128, g1, be1, scale + 64, shift + 64, N);

    // ---- layer 2 ----
    transform64<<<gt, 256, 0, stream>>>(h1, scale + 64, shift + 64, Wl2, Wr2, bl2, yl, h0, N);
    gather_kernel<<<gw2, 512, 0, stream>>>(yl, h0, col, seg, N);
    bn_stats<<<1024, 256, 0, stream>>>(h0, sums + 256, N);
    bn_finalize<<<1, 64, 0, stream>>>(sums + 256, g2, be2, scale + 128, shift + 128, N);

    out_kernel<<<(N + 3) / 4, 256, 0, stream>>>(h0, scale + 128, shift + 128, Wo, bo, (float*)d_out, N);
}

// Round 10
// 323.785 us; speedup vs baseline: 4.0601x; 1.1043x over previous
//
#include <hip/hip_runtime.h>

#define EPSV 1e-5f
#define REP 8                // replica count for superbucket counters (keyed blockIdx&7)
#define SBCAP 1280           // per-(replica,superbucket) window: mean 1024, sd 32 -> +8 sd
#define CWIN 16640           // per-superbucket col window: 8192 edges +8sd + pads (512*15), rounded

static __device__ __forceinline__ ushort f2bf(float f) {
    unsigned u = __float_as_uint(f);
    unsigned r = (u + 0x7FFF + ((u >> 16) & 1)) >> 16;   // RTNE
    return (ushort)r;
}

// ---------------- CSR build: super-bucket counting sort ----------------
// (unchanged from R9 — scatter ~30us, build ~30us)

__global__ __launch_bounds__(256) void sb_scatter(
    const int* __restrict__ src, const int* __restrict__ dst,
    int* __restrict__ sbcnt, int* __restrict__ bbuf, int E, int NSB)
{
    __shared__ int hist[512];
    __shared__ int gbase[512];
    int t = threadIdx.x;
    int r = blockIdx.x & (REP - 1);
    for (int i = t; i < NSB; i += 256) hist[i] = 0;
    __syncthreads();

    int base_i = (blockIdx.x * 256 + t) * 8;
    int d[8], s[8], rk[8];
    int m = E - base_i; m = m < 0 ? 0 : (m > 8 ? 8 : m);
    if (m == 8) {
        int4 da = *reinterpret_cast<const int4*>(dst + base_i);
        int4 db = *reinterpret_cast<const int4*>(dst + base_i + 4);
        int4 sa = *reinterpret_cast<const int4*>(src + base_i);
        int4 sb4 = *reinterpret_cast<const int4*>(src + base_i + 4);
        d[0] = da.x; d[1] = da.y; d[2] = da.z; d[3] = da.w;
        d[4] = db.x; d[5] = db.y; d[6] = db.z; d[7] = db.w;
        s[0] = sa.x; s[1] = sa.y; s[2] = sa.z; s[3] = sa.w;
        s[4] = sb4.x; s[5] = sb4.y; s[6] = sb4.z; s[7] = sb4.w;
    } else {
        for (int k = 0; k < m; ++k) { d[k] = dst[base_i + k]; s[k] = src[base_i + k]; }
    }
    for (int k = 0; k < m; ++k)
        rk[k] = atomicAdd(&hist[d[k] >> 9], 1);
    __syncthreads();

    for (int i = t; i < NSB; i += 256) {
        int c = hist[i];
        gbase[i] = c ? atomicAdd(&sbcnt[(r * NSB + i) * 16], c) : 0;
    }
    __syncthreads();

    for (int k = 0; k < m; ++k) {
        int sbk = d[k] >> 9;
        int pos = gbase[sbk] + rk[k];
        if (pos < SBCAP)
            bbuf[(size_t)(r * NSB + sbk) * SBCAP + pos] = ((d[k] & 511) << 17) | s[k];
    }
}

__global__ __launch_bounds__(512) void sb_build(
    const int* __restrict__ sbcnt, const int* __restrict__ bbuf,
    int2* __restrict__ seg, int* __restrict__ col, int n, int NSB)
{
    __shared__ int cnt[512], off[512], cur[512];
    int sb = blockIdx.x;
    int node0 = sb << 9;
    int t = threadIdx.x;
    cnt[t] = 0;
    __syncthreads();

    for (int r = 0; r < REP; ++r) {
        int c = min(sbcnt[(r * NSB + sb) * 16], SBCAP);
        const int* __restrict__ w = bbuf + (size_t)(r * NSB + sb) * SBCAP;
        for (int i = t; i < c; i += 512) atomicAdd(&cnt[w[i] >> 17], 1);
    }
    __syncthreads();

    if (t < 64) {                       // wave 0: scan of padded counts (8/lane)
        int v[8]; int run = 0;
#pragma unroll
        for (int k = 0; k < 8; ++k) {
            v[k] = run;
            run += (cnt[t * 8 + k] + 15) & ~15;
        }
        int pre = run;
        for (int dd = 1; dd < 64; dd <<= 1) {
            int tm = __shfl_up(pre, dd);
            if (t >= dd) pre += tm;
        }
        int lane_excl = pre - run;
#pragma unroll
        for (int k = 0; k < 8; ++k) off[t * 8 + k] = lane_excl + v[k];
    }
    __syncthreads();

    int colbase = sb * CWIN;
    {
        int node = node0 + t;
        if (node < n) seg[node] = make_int2(colbase + off[t], cnt[t]);
        cur[t] = off[t];
    }
    __syncthreads();

    for (int r = 0; r < REP; ++r) {
        int c = min(sbcnt[(r * NSB + sb) * 16], SBCAP);
        const int* __restrict__ w = bbuf + (size_t)(r * NSB + sb) * SBCAP;
        for (int i = t; i < c; i += 512) {
            int e = w[i];
            int p = atomicAdd(&cur[e >> 17], 1);
            col[colbase + p] = e & 0x1FFFF;
        }
    }
    __syncthreads();
    {
        int pend = off[t] + ((cnt[t] + 15) & ~15);
        for (int p = off[t] + cnt[t]; p < pend; ++p) col[colbase + p] = n;
    }
}

// ---------------- transform, DIN=7: yl = x@Wl (bf16) ; h = x@Wr + bl ----------------

__global__ __launch_bounds__(512) void transform7(
    const float* __restrict__ x,
    const float* __restrict__ Wl, const float* __restrict__ bl, const float* __restrict__ Wr,
    ushort* __restrict__ yl, float* __restrict__ h, int n)
{
    __shared__ float swl[7 * 64], swr[7 * 64], sbl[64];
    for (int i = threadIdx.x; i < 7 * 64; i += 512) { swl[i] = Wl[i]; swr[i] = Wr[i]; }
    if (threadIdx.x < 64) sbl[threadIdx.x] = bl[threadIdx.x];
    __syncthreads();

    if (blockIdx.x == 0 && threadIdx.x < 64) yl[(size_t)n * 64 + threadIdx.x] = 0;  // pad row

    int lane = threadIdx.x & 63;
    int node = blockIdx.x * 8 + (threadIdx.x >> 6);
    if (node >= n) return;

    float xv = (lane < 7) ? x[(size_t)node * 7 + lane] : 0.f;
    float hl = 0.f, hr = sbl[lane];
#pragma unroll
    for (int k = 0; k < 7; ++k) {
        float xk = __shfl(xv, k);
        hl += xk * swl[k * 64 + lane];
        hr += xk * swr[k * 64 + lane];
    }
    yl[(size_t)node * 64 + lane] = f2bf(hl);
    h[(size_t)node * 64 + lane] = hr;
}

// ---------------- transform, DIN=64: z = relu(BN(zin)); yl = z@Wl (bf16); h = z@Wr + bl ----

__global__ __launch_bounds__(256) void transform64(
    const float* __restrict__ zin, const float* __restrict__ scale, const float* __restrict__ shift,
    const float* __restrict__ Wl, const float* __restrict__ Wr, const float* __restrict__ bl,
    ushort* __restrict__ yl, float* __restrict__ h, int n)
{
    __shared__ float zt[64][68];
    __shared__ float swl[64 * 64];
    __shared__ float swr[64 * 64];
    __shared__ float ssc[64], ssh[64], sbl[64];

    int t = threadIdx.x;
    if (t < 64) { ssc[t] = scale[t]; ssh[t] = shift[t]; sbl[t] = bl[t]; }
    for (int i = t; i < 4096; i += 256) { swl[i] = Wl[i]; swr[i] = Wr[i]; }
    __syncthreads();

    int node0 = blockIdx.x * 64;
    {
        int m = t >> 2, c4 = (t & 3) * 16;
        int gm = node0 + m;
        if (gm < n) {
            const float4* zp = reinterpret_cast<const float4*>(zin + (size_t)gm * 64 + c4);
#pragma unroll
            for (int j = 0; j < 4; ++j) {
                float4 v = zp[j];
                int c = c4 + j * 4;
                v.x = fmaxf(v.x * ssc[c + 0] + ssh[c + 0], 0.f);
                v.y = fmaxf(v.y * ssc[c + 1] + ssh[c + 1], 0.f);
                v.z = fmaxf(v.z * ssc[c + 2] + ssh[c + 2], 0.f);
                v.w = fmaxf(v.w * ssc[c + 3] + ssh[c + 3], 0.f);
                zt[m][c + 0] = v.x; zt[m][c + 1] = v.y; zt[m][c + 2] = v.z; zt[m][c + 3] = v.w;
            }
        } else {
#pragma unroll
            for (int j = 0; j < 16; ++j) zt[m][c4 + j] = 0.f;
        }
    }
    __syncthreads();

    int ng = t >> 4;            // nodes ng*4..+3
    int cg = t & 15;            // cg<8 -> Wl (yl out), cg>=8 -> Wr (h out)
    int mb = ng * 4;
    const float* sw = (cg < 8) ? swl : swr;
    int c0 = (cg & 7) * 8;

    float acc[4][8];
#pragma unroll
    for (int i = 0; i < 4; ++i)
#pragma unroll
        for (int j = 0; j < 8; ++j) acc[i][j] = 0.f;

#pragma unroll 4
    for (int k = 0; k < 64; ++k) {
        float z0 = zt[mb + 0][k];
        float z1 = zt[mb + 1][k];
        float z2 = zt[mb + 2][k];
        float z3 = zt[mb + 3][k];
        float4 wa = *reinterpret_cast<const float4*>(sw + k * 64 + c0);
        float4 wb = *reinterpret_cast<const float4*>(sw + k * 64 + c0 + 4);
        float w[8] = {wa.x, wa.y, wa.z, wa.w, wb.x, wb.y, wb.z, wb.w};
#pragma unroll
        for (int j = 0; j < 8; ++j) {
            acc[0][j] += z0 * w[j];
            acc[1][j] += z1 * w[j];
            acc[2][j] += z2 * w[j];
            acc[3][j] += z3 * w[j];
        }
    }

#pragma unroll
    for (int i = 0; i < 4; ++i) {
        int gm = node0 + mb + i;
        if (gm >= n) continue;
        if (cg < 8) {
            uint4 pk;
            pk.x = (unsigned)f2bf(acc[i][0]) | ((unsigned)f2bf(acc[i][1]) << 16);
            pk.y = (unsigned)f2bf(acc[i][2]) | ((unsigned)f2bf(acc[i][3]) << 16);
            pk.z = (unsigned)f2bf(acc[i][4]) | ((unsigned)f2bf(acc[i][5]) << 16);
            pk.w = (unsigned)f2bf(acc[i][6]) | ((unsigned)f2bf(acc[i][7]) << 16);
            *reinterpret_cast<uint4*>(yl + (size_t)gm * 64 + c0) = pk;
        } else {
            float* dp = h + (size_t)gm * 64 + c0;
            *reinterpret_cast<float4*>(dp) =
                make_float4(acc[i][0] + sbl[c0 + 0], acc[i][1] + sbl[c0 + 1],
                            acc[i][2] + sbl[c0 + 2], acc[i][3] + sbl[c0 + 3]);
            *reinterpret_cast<float4*>(dp + 4) =
                make_float4(acc[i][4] + sbl[c0 + 4], acc[i][5] + sbl[c0 + 5],
                            acc[i][6] + sbl[c0 + 6], acc[i][7] + sbl[c0 + 7]);
        }
    }
}

// ---------------- gather + fused BN stats ----------------
// Persistent grid (1024 blocks x 8 waves). Wave per node. Lane = (group g =
// lane>>3, octet s = lane&7): group g reads neighbor g's yl row as ONE dwordx4
// at byte offset s*16 -> 8 rows per VMEM instruction (4x fewer than dword
// scheme). Cross-group reduce via shfl_xor(8/16/32); lanes g<2 do the float4
// h RMW and accumulate BN stats; 128 global atomics per block at the end
// (same flush count as the old standalone bn_stats).

__global__ __launch_bounds__(512) void gather_kernel(
    const ushort* __restrict__ yl, float* __restrict__ h,
    const int* __restrict__ col, const int2* __restrict__ seg,
    float* __restrict__ sums, int n)
{
    __shared__ float ls[128];
    int t = threadIdx.x;
    if (t < 128) ls[t] = 0.f;
    __syncthreads();

    int lane = t & 63;
    int g = lane >> 3, s = lane & 7;
    const unsigned* __restrict__ ylu = reinterpret_cast<const unsigned*>(yl);  // row stride 32

    float ss0 = 0.f, ss1 = 0.f, ss2 = 0.f, ss3 = 0.f;
    float sq0 = 0.f, sq1 = 0.f, sq2 = 0.f, sq3 = 0.f;

    int nw = gridDim.x * 8;
    for (int node = blockIdx.x * 8 + (t >> 6); node < n; node += nw) {
        int2 sc = seg[node];
        int s0  = __builtin_amdgcn_readfirstlane(sc.x);
        int deg = __builtin_amdgcn_readfirstlane(sc.y);
        int pc  = (deg + 15) & ~15;
        const int* __restrict__ cp = col + s0;

        float a0 = 0.f, a1 = 0.f, a2 = 0.f, a3 = 0.f;
        float a4 = 0.f, a5 = 0.f, a6 = 0.f, a7 = 0.f;
        for (int j0 = 0; j0 < pc; j0 += 16) {
            int i0 = cp[j0 + g];
            int i1 = cp[j0 + 8 + g];
            uint4 ua = *reinterpret_cast<const uint4*>(ylu + ((size_t)i0 << 5) + s * 4);
            uint4 ub = *reinterpret_cast<const uint4*>(ylu + ((size_t)i1 << 5) + s * 4);
            a0 += __uint_as_float(ua.x << 16);        a1 += __uint_as_float(ua.x & 0xFFFF0000u);
            a2 += __uint_as_float(ua.y << 16);        a3 += __uint_as_float(ua.y & 0xFFFF0000u);
            a4 += __uint_as_float(ua.z << 16);        a5 += __uint_as_float(ua.z & 0xFFFF0000u);
            a6 += __uint_as_float(ua.w << 16);        a7 += __uint_as_float(ua.w & 0xFFFF0000u);
            a0 += __uint_as_float(ub.x << 16);        a1 += __uint_as_float(ub.x & 0xFFFF0000u);
            a2 += __uint_as_float(ub.y << 16);        a3 += __uint_as_float(ub.y & 0xFFFF0000u);
            a4 += __uint_as_float(ub.z << 16);        a5 += __uint_as_float(ub.z & 0xFFFF0000u);
            a6 += __uint_as_float(ub.w << 16);        a7 += __uint_as_float(ub.w & 0xFFFF0000u);
        }
        // reduce across the 8 groups (lane bits 3..5)
#pragma unroll
        for (int mk = 8; mk <= 32; mk <<= 1) {
            a0 += __shfl_xor(a0, mk); a1 += __shfl_xor(a1, mk);
            a2 += __shfl_xor(a2, mk); a3 += __shfl_xor(a3, mk);
            a4 += __shfl_xor(a4, mk); a5 += __shfl_xor(a5, mk);
            a6 += __shfl_xor(a6, mk); a7 += __shfl_xor(a7, mk);
        }
        if (g < 2) {
            float inv = 1.f / (float)max(deg, 1);
            float b0 = (g ? a4 : a0), b1 = (g ? a5 : a1), b2 = (g ? a6 : a2), b3 = (g ? a7 : a3);
            float* hp = h + (size_t)node * 64 + s * 8 + g * 4;
            float4 hv = *reinterpret_cast<float4*>(hp);
            hv.x += b0 * inv; hv.y += b1 * inv; hv.z += b2 * inv; hv.w += b3 * inv;
            *reinterpret_cast<float4*>(hp) = hv;
            ss0 += hv.x; sq0 += hv.x * hv.x;
            ss1 += hv.y; sq1 += hv.y * hv.y;
            ss2 += hv.z; sq2 += hv.z * hv.z;
            ss3 += hv.w; sq3 += hv.w * hv.w;
        }
    }
    if (g < 2) {
        int cb = s * 8 + g * 4;
        atomicAdd(&ls[cb + 0], ss0); atomicAdd(&ls[cb + 1], ss1);
        atomicAdd(&ls[cb + 2], ss2); atomicAdd(&ls[cb + 3], ss3);
        atomicAdd(&ls[64 + cb + 0], sq0); atomicAdd(&ls[64 + cb + 1], sq1);
        atomicAdd(&ls[64 + cb + 2], sq2); atomicAdd(&ls[64 + cb + 3], sq3);
    }
    __syncthreads();
    if (t < 128) atomicAdd(&sums[t], ls[t]);
}

__global__ void bn_finalize(const float* __restrict__ sums, const float* __restrict__ g,
                            const float* __restrict__ be, float* __restrict__ scale,
                            float* __restrict__ shift, int n) {
    int c = threadIdx.x;
    if (c < 64) {
        float inv_n = 1.f / (float)n;
        float mu = sums[c] * inv_n;
        float var = sums[64 + c] * inv_n - mu * mu;
        float sc = g[c] * rsqrtf(var + EPSV);
        scale[c] = sc;
        shift[c] = be[c] - mu * sc;
    }
}

// ---------------- output head: relu(BN(h)) @ Wo + bo ----------------

__global__ __launch_bounds__(256) void out_kernel(const float* __restrict__ h,
                                                  const float* __restrict__ scale,
                                                  const float* __restrict__ shift,
                                                  const float* __restrict__ Wo,
                                                  const float* __restrict__ bo,
                                                  float* __restrict__ out, int n) {
    int lane = threadIdx.x & 63;
    int wave = threadIdx.x >> 6;
    int node = blockIdx.x * 4 + wave;
    if (node >= n) return;
    float v = h[(size_t)node * 64 + lane];
    v = fmaxf(v * scale[lane] + shift[lane], 0.f);
    float p = v * Wo[lane];
    for (int d = 32; d > 0; d >>= 1) p += __shfl_xor(p, d);
    if (lane == 0) out[node] = p + bo[0];
}

// ---------------- launch ----------------

extern "C" void kernel_launch(void* const* d_in, const int* in_sizes, int n_in,
                              void* d_out, int out_size, void* d_ws, size_t ws_size,
                              hipStream_t stream) {
    const float* x   = (const float*)d_in[0];
    const int*   ei  = (const int*)d_in[1];
    const float* Wl0 = (const float*)d_in[2];
    const float* bl0 = (const float*)d_in[3];
    const float* Wr0 = (const float*)d_in[4];
    const float* g0  = (const float*)d_in[5];
    const float* be0 = (const float*)d_in[6];
    const float* Wl1 = (const float*)d_in[7];
    const float* bl1 = (const float*)d_in[8];
    const float* Wr1 = (const float*)d_in[9];
    const float* g1  = (const float*)d_in[10];
    const float* be1 = (const float*)d_in[11];
    const float* Wl2 = (const float*)d_in[12];
    const float* bl2 = (const float*)d_in[13];
    const float* Wr2 = (const float*)d_in[14];
    const float* g2  = (const float*)d_in[15];
    const float* be2 = (const float*)d_in[16];
    const float* Wo  = (const float*)d_in[17];
    const float* bo  = (const float*)d_in[18];

    const int N = in_sizes[0] / 7;
    const int E = in_sizes[1] / 2;
    const int NSB = (N + 511) / 512;
    const int* srcp = ei;
    const int* dstp = ei + E;

    char* ws = (char*)d_ws;
    size_t off = 0;
    auto walloc = [&](size_t bytes) -> void* {
        void* p = ws + off;
        off = (off + bytes + 255) & ~(size_t)255;
        return p;
    };
    int*    sbcnt  = (int*)walloc((size_t)REP * NSB * 16 * sizeof(int));  // 1 counter per 64B line
    int*    bbuf   = (int*)walloc((size_t)REP * NSB * SBCAP * sizeof(int));
    int2*   seg    = (int2*)walloc((size_t)(N + 1) * sizeof(int2));
    int*    col    = (int*)walloc((size_t)NSB * CWIN * sizeof(int));
    float*  sums   = (float*)walloc(3 * 128 * sizeof(float));
    float*  scale  = (float*)walloc(3 * 64 * sizeof(float));
    float*  shift  = (float*)walloc(3 * 64 * sizeof(float));
    ushort* yl     = (ushort*)walloc(((size_t)N + 1) * 64 * sizeof(ushort));  // row N = zeros
    float*  h0     = (float*)walloc((size_t)N * 64 * sizeof(float));
    float*  h1     = (float*)walloc((size_t)N * 64 * sizeof(float));

    hipMemsetAsync(sbcnt, 0, (size_t)REP * NSB * 16 * sizeof(int), stream);
    hipMemsetAsync(sums, 0, 3 * 128 * sizeof(float), stream);

    sb_scatter<<<(E + 2047) / 2048, 256, 0, stream>>>(srcp, dstp, sbcnt, bbuf, E, NSB);
    sb_build<<<NSB, 512, 0, stream>>>(sbcnt, bbuf, seg, col, N, NSB);

    const int gw  = (N + 7) / 8;      // wave-per-node grids (512 threads)
    const int gp  = 1024;             // persistent gather grid
    const int gt  = (N + 63) / 64;    // transform64 tiles

    // ---- layer 0 ----
    transform7<<<gw, 512, 0, stream>>>(x, Wl0, bl0, Wr0, yl, h0, N);
    gather_kernel<<<gp, 512, 0, stream>>>(yl, h0, col, seg, sums, N);
    bn_finalize<<<1, 64, 0, stream>>>(sums, g0, be0, scale, shift, N);

    // ---- layer 1 ----
    transform64<<<gt, 256, 0, stream>>>(h0, scale, shift, Wl1, Wr1, bl1, yl, h1, N);
    gather_kernel<<<gp, 512, 0, stream>>>(yl, h1, col, seg, sums + 128, N);
    bn_finalize<<<1, 64, 0, stream>>>(sums + 128, g1, be1, scale + 64, shift + 64, N);

    // ---- layer 2 ----
    transform64<<<gt, 256, 0, stream>>>(h1, scale + 64, shift + 64, Wl2, Wr2, bl2, yl, h0, N);
    gather_kernel<<<gp, 512, 0, stream>>>(yl, h0, col, seg, sums + 256, N);
    bn_finalize<<<1, 64, 0, stream>>>(sums + 256, g2, be2, scale + 128, shift + 128, N);

    out_kernel<<<(N + 3) / 4, 256, 0, stream>>>(h0, scale + 128, shift + 128, Wo, bo, (float*)d_out, N);
}